// Round 9
// baseline (26975.800 us; speedup 1.0000x reference)
//
#include <hip/hip_runtime.h>
#include <hip/hip_bf16.h>

#define NN 20000
#define NE 320000
#define H  128
#define NL 4

typedef unsigned int uint;
typedef unsigned short u16;

static constexpr size_t NNH = (size_t)NN*H;   // 2,560,000
static constexpr size_t NEH = (size_t)NE*H;   // 40,960,000

// ---------- workspace layout (bytes), total 261,545,344 (< 256MiB = 268,435,456) ----------
static constexpr size_t OFF_H5    = 0;                                // h5   [5][NN][H] f32
static constexpr size_t OFF_UPRE  = OFF_H5    + 5*NNH*4;              // upre [4][NN][H] bf16
static constexpr size_t OFF_LNST  = OFF_UPRE  + 4*NNH*2;              // lnst [4][NN][2] f32 (mu, rstd)
static constexpr size_t OFF_E     = OFF_LNST  + (size_t)4*NN*2*4;     // e [NE][H] bf16 (fwd + replay)
static constexpr size_t OFF_DE    = OFF_E     + NEH*2;                // de [NE][H] bf16
static constexpr size_t OFF_AGG   = OFF_DE    + NEH*2;                // agg/dagg [NN][H] f32 (shared)
static constexpr size_t OFF_DH    = OFF_AGG   + NNH*4;                // dh [NN][H] f32
static constexpr size_t OFF_DIST  = OFF_DH    + NNH*4;                // dist [NE] f32
static constexpr size_t OFF_DDIST = OFF_DIST  + (size_t)NE*4;         // ddist [NE] f32
static constexpr size_t OFF_DPOS  = OFF_DDIST + (size_t)NE*4;         // dpos [NN][3] f32
static constexpr size_t OFF_WMT   = OFF_DPOS  + (size_t)NN*3*4;       // WmT [NL][128][388] f32
static constexpr size_t OFF_WET   = OFF_WMT   + (size_t)NL*128*388*4; // WeT [NL][128][384] f32
static constexpr size_t OFF_WUT   = OFF_WET   + (size_t)NL*128*384*4; // WuT [NL][128][256] f32
static constexpr size_t WS_NEED   = OFF_WUT   + (size_t)NL*128*256*4;

// ---------- helpers ----------
__device__ __forceinline__ float sigm(float x){ return 1.f/(1.f+__expf(-x)); }
__device__ __forceinline__ float siluf(float x){ return x*sigm(x); }
__device__ __forceinline__ float dsilu(float x){ float s=sigm(x); return s*(1.f + x*(1.f-s)); }
__device__ __forceinline__ u16 f2bf(float x){        // RNE f32 -> bf16
  uint u = __float_as_uint(x);
  uint r = (u + 0x7fffu + ((u>>16)&1u)) >> 16;
  return (u16)r;
}
__device__ __forceinline__ float bf2f(u16 v){ return __uint_as_float(((uint)v)<<16); }
__device__ __forceinline__ uint pack2(float a, float b){ return (uint)f2bf(a) | ((uint)f2bf(b)<<16); }
__device__ __forceinline__ void ld_bf8(const u16* p, float* v){
  uint4 q = *(const uint4*)p;
  v[0]=__uint_as_float(q.x<<16); v[1]=__uint_as_float(q.x&0xffff0000u);
  v[2]=__uint_as_float(q.y<<16); v[3]=__uint_as_float(q.y&0xffff0000u);
  v[4]=__uint_as_float(q.z<<16); v[5]=__uint_as_float(q.z&0xffff0000u);
  v[6]=__uint_as_float(q.w<<16); v[7]=__uint_as_float(q.w&0xffff0000u);
}
__device__ __forceinline__ void st_bf8(u16* p, const float* v){
  uint4 o;
  o.x = pack2(v[0],v[1]); o.y = pack2(v[2],v[3]);
  o.z = pack2(v[4],v[5]); o.w = pack2(v[6],v[7]);
  *(uint4*)p = o;
}

__device__ __forceinline__ float2 blockSum2_128(float a, float b, float* sb){
  #pragma unroll
  for (int off=32; off>0; off>>=1){ a += __shfl_down(a, off); b += __shfl_down(b, off); }
  int t = threadIdx.x;
  if ((t&63)==0){ sb[(t>>6)*2+0]=a; sb[(t>>6)*2+1]=b; }
  __syncthreads();
  float2 r; r.x = sb[0]+sb[2]; r.y = sb[1]+sb[3];
  __syncthreads();
  return r;
}

// ---------- diagnostic (f32 sentinel, 4000+MiB) ----------
__global__ void diag_k(float* out, float v){ out[0] = v; }

// ---------- weight transposes ----------
__global__ void transpose_w(const float* __restrict__ Wm, const float* __restrict__ We,
                            const float* __restrict__ Wu,
                            float* __restrict__ WmT, float* __restrict__ WeT,
                            float* __restrict__ WuT){
  int idx = blockIdx.x*blockDim.x + threadIdx.x;
  int stride = gridDim.x*blockDim.x;
  for (int i=idx; i<NL*128*388; i+=stride){
    int l = i/(128*388), r = i - l*128*388, k = r/388, j = r - k*388;
    WmT[i] = (j<385) ? Wm[((size_t)l*385 + j)*H + k] : 0.f;
  }
  for (int i=idx; i<NL*128*384; i+=stride){
    int l = i/(128*384), r = i - l*128*384, k = r/384, j = r - k*384;
    WeT[i] = We[((size_t)l*384 + j)*H + k];
  }
  for (int i=idx; i<NL*128*256; i+=stride){
    int l = i/(128*256), r = i - l*128*256, k = r/256, j = r - k*256;
    WuT[i] = Wu[((size_t)l*256 + j)*H + k];
  }
}

// ---------- small kernels ----------
__global__ __launch_bounds__(128) void node_emb(const float* __restrict__ x,
                                                const float* __restrict__ Wn,
                                                const float* __restrict__ bn,
                                                float* __restrict__ h){
  __shared__ float xs[16];
  int n = blockIdx.x, c = threadIdx.x;
  if (c < 16) xs[c] = x[(size_t)n*16 + c];
  __syncthreads();
  float s = bn[c];
  #pragma unroll
  for (int k=0;k<16;k++) s = fmaf(xs[k], Wn[k*H + c], s);
  h[(size_t)n*H + c] = s;
}

__global__ __launch_bounds__(256) void edge_emb(const float* __restrict__ ea,
                                                const float* __restrict__ We5,
                                                const float* __restrict__ be,
                                                u16* __restrict__ ebuf){
  int e = blockIdx.x*2 + (threadIdx.x>>7);
  int c = threadIdx.x & 127;
  const float* row = ea + (size_t)e*8;
  float v;
  if (c < 3) v = row[c];
  else {
    int j = c-3;
    float s = be[j];
    #pragma unroll
    for (int k=0;k<5;k++) s = fmaf(row[3+k], We5[k*125 + j], s);
    v = s;
  }
  ebuf[(size_t)e*H + c] = f2bf(v);
}

__global__ void rel_dist(const float* __restrict__ y, const int* __restrict__ ei,
                         float* __restrict__ dist){
  int e = blockIdx.x*256 + threadIdx.x;
  if (e >= NE) return;
  int s = ei[e], d = ei[NE+e];
  float rx = y[(size_t)d*6+0] - y[(size_t)s*6+0];
  float ry = y[(size_t)d*6+1] - y[(size_t)s*6+1];
  float rz = y[(size_t)d*6+2] - y[(size_t)s*6+2];
  dist[e] = sqrtf(rx*rx + ry*ry + rz*rz + 1e-8f);
}

// ---------- edge GEMM forward (MODE 0 = msg->agg, 1 = eu e+=silu in-place) ----------
template<int MODE>
__global__ __launch_bounds__(256) void efwd(
    const float* __restrict__ hb, u16* __restrict__ eb,
    const float* __restrict__ dist, const int* __restrict__ ei,
    const float* __restrict__ W, const float* __restrict__ bias,
    float* __restrict__ agg)
{
  __shared__ __align__(16) float Ast[16][128];
  __shared__ __align__(16) float Bs[16][128];
  __shared__ int sidx[128], didx[128];
  const int t = threadIdx.x;
  const int e0 = blockIdx.x * 128;
  if (t < 128){ sidx[t] = ei[e0+t]; didx[t] = ei[NE+e0+t]; }
  __syncthreads();
  float acc[8][8];
  #pragma unroll
  for (int i=0;i<8;i++){
    #pragma unroll
    for (int j=0;j<8;j++) acc[i][j]=0.f;
  }
  const int srow = t>>1, kh = (t&1)*8;
  const int r0 = (t>>4)*8, c0 = (t&15)*8;

  for (int k0=0; k0<384; k0+=16){
    float av8[8];
    if (k0 < 256){
      const float* p = hb + (size_t)((k0<128)?sidx[srow]:didx[srow])*H + (k0&127) + kh;
      float4 v0 = *(const float4*)p, v1 = *(const float4*)(p+4);
      av8[0]=v0.x;av8[1]=v0.y;av8[2]=v0.z;av8[3]=v0.w;
      av8[4]=v1.x;av8[5]=v1.y;av8[6]=v1.z;av8[7]=v1.w;
    } else {
      ld_bf8(eb + (size_t)(e0+srow)*H + (k0-256) + kh, av8);
    }
    #pragma unroll
    for (int j=0;j<8;j++) Ast[kh+j][srow] = av8[j];
    #pragma unroll
    for (int i=0;i<2;i++){
      int j4 = t + i*256;
      int kk = j4>>5, cc = (j4&31)*4;
      *(float4*)&Bs[kk][cc] = *(const float4*)&W[(size_t)(k0+kk)*H + cc];
    }
    __syncthreads();
    #pragma unroll
    for (int kk=0;kk<16;kk++){
      float4 a0 = *(const float4*)&Ast[kk][r0];
      float4 a1 = *(const float4*)&Ast[kk][r0+4];
      float4 b0 = *(const float4*)&Bs[kk][c0];
      float4 b1 = *(const float4*)&Bs[kk][c0+4];
      float av[8] = {a0.x,a0.y,a0.z,a0.w,a1.x,a1.y,a1.z,a1.w};
      float bv[8] = {b0.x,b0.y,b0.z,b0.w,b1.x,b1.y,b1.z,b1.w};
      #pragma unroll
      for (int r=0;r<8;r++){
        #pragma unroll
        for (int c=0;c<8;c++) acc[r][c] = fmaf(av[r], bv[c], acc[r][c]);
      }
    }
    __syncthreads();
  }

  float bi[8];
  { float4 x0 = *(const float4*)&bias[c0]; float4 x1 = *(const float4*)&bias[c0+4];
    bi[0]=x0.x;bi[1]=x0.y;bi[2]=x0.z;bi[3]=x0.w;bi[4]=x1.x;bi[5]=x1.y;bi[6]=x1.z;bi[7]=x1.w; }
  if (MODE==0){
    float wd[8];
    float4 y0=*(const float4*)&W[(size_t)384*H + c0];
    float4 y1=*(const float4*)&W[(size_t)384*H + c0+4];
    wd[0]=y0.x;wd[1]=y0.y;wd[2]=y0.z;wd[3]=y0.w;wd[4]=y1.x;wd[5]=y1.y;wd[6]=y1.z;wd[7]=y1.w;
    #pragma unroll
    for (int r=0;r<8;r++){
      int eidx = e0 + r0 + r;
      float dv = dist[eidx];
      int dn = didx[r0+r];
      #pragma unroll
      for (int c=0;c<8;c++){
        float v = acc[r][c] + bi[c] + dv*wd[c];
        atomicAdd(&agg[(size_t)dn*H + c0 + c], siluf(v));
      }
    }
  } else {
    #pragma unroll
    for (int r=0;r<8;r++){
      u16* ep = eb + (size_t)(e0 + r0 + r)*H + c0;
      float ev[8]; ld_bf8(ep, ev);
      #pragma unroll
      for (int c=0;c<8;c++) ev[c] += siluf(acc[r][c]+bi[c]);
      st_bf8(ep, ev);
    }
  }
}

// ---------- fused edge backward: recompute pre, A=mul*dsilu(pre), A@WT ----------
template<int MODE>
__global__ __launch_bounds__(256) void ebwd(
    const float* __restrict__ hb, const u16* __restrict__ eb,
    const float* __restrict__ dist, const int* __restrict__ ei,
    const float* __restrict__ W, const float* __restrict__ bias,
    const float* __restrict__ mulf, const float* __restrict__ WT,
    float* __restrict__ dh, u16* __restrict__ de, float* __restrict__ ddist)
{
  const int ldB = (MODE==0) ? 388 : 384;
  __shared__ __align__(16) float Ast[16][128];
  __shared__ __align__(16) float Bs[16][128];
  __shared__ int sidx[128], didx[128];
  const int t = threadIdx.x;
  const int e0 = blockIdx.x * 128;
  if (t < 128){ sidx[t] = ei[e0+t]; didx[t] = ei[NE+e0+t]; }
  __syncthreads();
  const int srow = t>>1, kh = (t&1)*8;
  const int r0 = (t>>4)*8, c0 = (t&15)*8;

  // ---- phase 1: pre = [h_s, h_d, e (,dist)] @ W + b ----
  float pre[8][8];
  #pragma unroll
  for (int i=0;i<8;i++){
    #pragma unroll
    for (int j=0;j<8;j++) pre[i][j]=0.f;
  }
  for (int k0=0; k0<384; k0+=16){
    float av8[8];
    if (k0 < 256){
      const float* p = hb + (size_t)((k0<128)?sidx[srow]:didx[srow])*H + (k0&127) + kh;
      float4 v0 = *(const float4*)p, v1 = *(const float4*)(p+4);
      av8[0]=v0.x;av8[1]=v0.y;av8[2]=v0.z;av8[3]=v0.w;
      av8[4]=v1.x;av8[5]=v1.y;av8[6]=v1.z;av8[7]=v1.w;
    } else {
      ld_bf8(eb + (size_t)(e0+srow)*H + (k0-256) + kh, av8);
    }
    #pragma unroll
    for (int j=0;j<8;j++) Ast[kh+j][srow] = av8[j];
    #pragma unroll
    for (int i=0;i<2;i++){
      int j4 = t + i*256;
      int kk = j4>>5, cc = (j4&31)*4;
      *(float4*)&Bs[kk][cc] = *(const float4*)&W[(size_t)(k0+kk)*H + cc];
    }
    __syncthreads();
    #pragma unroll
    for (int kk=0;kk<16;kk++){
      float4 a0 = *(const float4*)&Ast[kk][r0];
      float4 a1 = *(const float4*)&Ast[kk][r0+4];
      float4 b0 = *(const float4*)&Bs[kk][c0];
      float4 b1 = *(const float4*)&Bs[kk][c0+4];
      float av[8] = {a0.x,a0.y,a0.z,a0.w,a1.x,a1.y,a1.z,a1.w};
      float bv[8] = {b0.x,b0.y,b0.z,b0.w,b1.x,b1.y,b1.z,b1.w};
      #pragma unroll
      for (int r=0;r<8;r++){
        #pragma unroll
        for (int c=0;c<8;c++) pre[r][c] = fmaf(av[r], bv[c], pre[r][c]);
      }
    }
    __syncthreads();
  }
  {
    float bi[8];
    float4 x0 = *(const float4*)&bias[c0]; float4 x1 = *(const float4*)&bias[c0+4];
    bi[0]=x0.x;bi[1]=x0.y;bi[2]=x0.z;bi[3]=x0.w;bi[4]=x1.x;bi[5]=x1.y;bi[6]=x1.z;bi[7]=x1.w;
    float wd[8] = {0,0,0,0,0,0,0,0};
    if (MODE==0){
      float4 y0=*(const float4*)&W[(size_t)384*H + c0];
      float4 y1=*(const float4*)&W[(size_t)384*H + c0+4];
      wd[0]=y0.x;wd[1]=y0.y;wd[2]=y0.z;wd[3]=y0.w;wd[4]=y1.x;wd[5]=y1.y;wd[6]=y1.z;wd[7]=y1.w;
    }
    #pragma unroll
    for (int r=0;r<8;r++){
      float dv = (MODE==0) ? dist[e0+r0+r] : 0.f;
      #pragma unroll
      for (int c=0;c<8;c++) pre[r][c] += bi[c] + dv*wd[c];
    }
  }

  // ---- phase 2: A = mul * dsilu(pre) (in registers) ----
  #pragma unroll
  for (int r=0;r<8;r++){
    float mv[8];
    if (MODE==0){
      const float* mp = mulf + (size_t)didx[r0+r]*H + c0;
      float4 m0 = *(const float4*)mp, m1 = *(const float4*)(mp+4);
      mv[0]=m0.x;mv[1]=m0.y;mv[2]=m0.z;mv[3]=m0.w;mv[4]=m1.x;mv[5]=m1.y;mv[6]=m1.z;mv[7]=m1.w;
    } else {
      ld_bf8(de + (size_t)(e0+r0+r)*H + c0, mv);
    }
    #pragma unroll
    for (int c=0;c<8;c++) pre[r][c] = mv[c]*dsilu(pre[r][c]);
  }

  // ---- phase 3: [dh_s | dh_d | de] = A @ WT  (K = 128) ----
  float pdist = 0.f;
  #pragma unroll 1
  for (int jc=0; jc<3; jc++){
    float acc[8][8];
    #pragma unroll
    for (int i=0;i<8;i++){
      #pragma unroll
      for (int j=0;j<8;j++) acc[i][j]=0.f;
    }
    #pragma unroll 1
    for (int k0=0; k0<128; k0+=16){
      __syncthreads();
      if (c0 == k0 || c0 == k0+8){
        int xb = c0 - k0;   // 0 or 8
        #pragma unroll
        for (int r=0;r<8;r++){
          #pragma unroll
          for (int cj=0;cj<8;cj++) Ast[xb+cj][r0+r] = pre[r][cj];
        }
      }
      #pragma unroll
      for (int i=0;i<2;i++){
        int j4 = t + i*256;
        int kk = j4>>5, cc = (j4&31)*4;
        *(float4*)&Bs[kk][cc] = *(const float4*)&WT[(size_t)(k0+kk)*ldB + jc*128 + cc];
      }
      __syncthreads();
      #pragma unroll
      for (int kk=0;kk<16;kk++){
        float4 a0 = *(const float4*)&Ast[kk][r0];
        float4 a1 = *(const float4*)&Ast[kk][r0+4];
        float4 b0 = *(const float4*)&Bs[kk][c0];
        float4 b1 = *(const float4*)&Bs[kk][c0+4];
        float av[8] = {a0.x,a0.y,a0.z,a0.w,a1.x,a1.y,a1.z,a1.w};
        float bv[8] = {b0.x,b0.y,b0.z,b0.w,b1.x,b1.y,b1.z,b1.w};
        #pragma unroll
        for (int r=0;r<8;r++){
          #pragma unroll
          for (int c=0;c<8;c++) acc[r][c] = fmaf(av[r], bv[c], acc[r][c]);
        }
      }
      if (MODE==0 && jc==2 && t<128){
        #pragma unroll
        for (int kk=0;kk<16;kk++)
          pdist = fmaf(Ast[kk][t], WT[(size_t)(k0+kk)*ldB + 384], pdist);
      }
    }
    if (jc==0){
      #pragma unroll
      for (int r=0;r<8;r++){
        int sn = sidx[r0+r];
        #pragma unroll
        for (int c=0;c<8;c++) atomicAdd(&dh[(size_t)sn*H + c0 + c], acc[r][c]);
      }
    } else if (jc==1){
      #pragma unroll
      for (int r=0;r<8;r++){
        int dn = didx[r0+r];
        #pragma unroll
        for (int c=0;c<8;c++) atomicAdd(&dh[(size_t)dn*H + c0 + c], acc[r][c]);
      }
    } else {
      #pragma unroll
      for (int r=0;r<8;r++){
        u16* ep = de + (size_t)(e0+r0+r)*H + c0;
        float ev[8]; ld_bf8(ep, ev);
        #pragma unroll
        for (int c=0;c<8;c++) ev[c] += acc[r][c];
        st_bf8(ep, ev);
      }
    }
  }
  if (MODE==0 && t<128) ddist[e0+t] += pdist;
}

// ---------- node update forward ----------
__global__ __launch_bounds__(128) void upd_fwd(
    const float* __restrict__ hin, const float* __restrict__ agg,
    const float* __restrict__ Wu, const float* __restrict__ bu,
    const float* __restrict__ g, const float* __restrict__ bln,
    u16* __restrict__ upre, float* __restrict__ lnst, float* __restrict__ hout)
{
  __shared__ float ha[256];
  __shared__ float sb[4];
  int n = blockIdx.x, c = threadIdx.x;
  float hv = hin[(size_t)n*H + c];
  ha[c] = hv;
  ha[128+c] = agg[(size_t)n*H + c];
  __syncthreads();
  float s = bu[c];
  #pragma unroll 4
  for (int k=0;k<256;k++) s = fmaf(ha[k], Wu[(size_t)k*H + c], s);
  upre[(size_t)n*H + c] = f2bf(s);
  float2 ms = blockSum2_128(s, s*s, sb);
  float mu = ms.x*(1.f/128.f);
  float var = ms.y*(1.f/128.f) - mu*mu;
  float rstd = rsqrtf(var + 1e-5f);
  if (c == 0){ lnst[(size_t)n*2+0] = mu; lnst[(size_t)n*2+1] = rstd; }
  float uh = (s - mu)*rstd;
  float un = uh*g[c] + bln[c];
  hout[(size_t)n*H + c] = hv + siluf(un);
}

// ---------- final MLP fused fwd+bwd -> dh ----------
__global__ __launch_bounds__(128) void final_fused(
    const float* __restrict__ h, const float* __restrict__ Wo, const float* __restrict__ bo,
    const float* __restrict__ Wh1, const float* __restrict__ bh1v,
    const float* __restrict__ Wh2, float* __restrict__ dh)
{
  __shared__ float sh[128], sf[64], sdz[32], sdf[64];
  int n = blockIdx.x, c = threadIdx.x;
  sh[c] = h[(size_t)n*H + c];
  __syncthreads();
  if (c < 64){
    float s = bo[c];
    #pragma unroll 4
    for (int k=0;k<128;k++) s = fmaf(sh[k], Wo[(size_t)k*64 + c], s);
    sf[c] = s;
  }
  __syncthreads();
  if (c < 32){
    float s = bh1v[c];
    #pragma unroll 4
    for (int j=0;j<64;j++) s = fmaf(sf[j], Wh1[(size_t)j*32 + c], s);
    sdz[c] = Wh2[c]*dsilu(s);
  }
  __syncthreads();
  if (c < 64){
    float s = 0.f;
    #pragma unroll 4
    for (int k=0;k<32;k++) s = fmaf(sdz[k], Wh1[(size_t)c*32 + k], s);
    sdf[c] = s;
  }
  __syncthreads();
  {
    float s = 0.f;
    #pragma unroll 4
    for (int j=0;j<64;j++) s = fmaf(sdf[j], Wo[(size_t)c*64 + j], s);
    dh[(size_t)n*H + c] = s;
  }
}

// ---------- node update backward ----------
__global__ __launch_bounds__(128) void upd_bwd(
    float* __restrict__ dh, float* __restrict__ dagg,
    const u16* __restrict__ upre, const float* __restrict__ lnst,
    const float* __restrict__ WuT,
    const float* __restrict__ g, const float* __restrict__ bln)
{
  __shared__ float sh[128];
  __shared__ float sb[4];
  int n = blockIdx.x, c = threadIdx.x;
  float up   = bf2f(upre[(size_t)n*H + c]);
  float mu   = lnst[(size_t)n*2+0];
  float rstd = lnst[(size_t)n*2+1];
  float uh = (up - mu)*rstd;
  float un = uh*g[c] + bln[c];
  float dhv = dh[(size_t)n*H + c];
  float dun = dhv * dsilu(un);
  float duh = dun * g[c];
  float2 m12 = blockSum2_128(duh, duh*uh, sb);
  float m1 = m12.x*(1.f/128.f), m2 = m12.y*(1.f/128.f);
  float dup = (duh - m1 - uh*m2)*rstd;
  sh[c] = dup;
  __syncthreads();
  float s0 = 0.f, s1 = 0.f;
  #pragma unroll 4
  for (int k=0;k<128;k++){
    float d = sh[k];
    s0 = fmaf(d, WuT[(size_t)k*256 + c], s0);
    s1 = fmaf(d, WuT[(size_t)k*256 + 128 + c], s1);
  }
  dh[(size_t)n*H + c] = dhv + s0;
  dagg[(size_t)n*H + c] = s1;
}

// ---------- dist -> dpos ----------
__global__ void rel_bwd(const float* __restrict__ y, const float* __restrict__ dist,
                        const float* __restrict__ ddist, const int* __restrict__ ei,
                        float* __restrict__ dpos){
  int e = blockIdx.x*256 + threadIdx.x;
  if (e >= NE) return;
  int s = ei[e], d = ei[NE+e];
  float gsc = ddist[e]/dist[e];
  #pragma unroll
  for (int i=0;i<3;i++){
    float dr = gsc*(y[(size_t)d*6+i] - y[(size_t)s*6+i]);
    atomicAdd(&dpos[(size_t)d*3+i],  dr);
    atomicAdd(&dpos[(size_t)s*3+i], -dr);
  }
}

// ---------- output: F32 (reference output dtype is float32; out_npz = 480KB) ----------
__global__ void out_k(const float* __restrict__ y, const float* __restrict__ dpos,
                      float* __restrict__ out){
  int n = blockIdx.x*256 + threadIdx.x;
  if (n >= NN) return;
  #pragma unroll
  for (int i=0;i<3;i++) out[(size_t)n*6+i]   =  y[(size_t)n*6+3+i];
  #pragma unroll
  for (int i=0;i<3;i++) out[(size_t)n*6+3+i] = -dpos[(size_t)n*3+i];
}

// ---------- host ----------
extern "C" void kernel_launch(void* const* d_in, const int* in_sizes, int n_in,
                              void* d_out, int out_size, void* d_ws, size_t ws_size,
                              hipStream_t stream)
{
  const float* y   = (const float*)d_in[0];
  const float* x   = (const float*)d_in[1];
  const float* ea  = (const float*)d_in[2];
  const int*   ei  = (const int*)d_in[3];
  const float* Wn  = (const float*)d_in[4];
  const float* bn  = (const float*)d_in[5];
  const float* We5 = (const float*)d_in[6];
  const float* be5 = (const float*)d_in[7];
  const float* Wm  = (const float*)d_in[8];
  const float* bm  = (const float*)d_in[9];
  const float* Wu  = (const float*)d_in[10];
  const float* bu  = (const float*)d_in[11];
  const float* lg  = (const float*)d_in[12];
  const float* lb  = (const float*)d_in[13];
  const float* We  = (const float*)d_in[14];
  const float* beu = (const float*)d_in[15];
  const float* Wo  = (const float*)d_in[16];
  const float* bo  = (const float*)d_in[17];
  const float* Wh1 = (const float*)d_in[18];
  const float* bh1v= (const float*)d_in[19];
  const float* Wh2 = (const float*)d_in[20];
  float* out = (float*)d_out;

  if (ws_size < WS_NEED){
    diag_k<<<1, 1, 0, stream>>>(out, 4000.f + (float)(ws_size >> 20));
    return;
  }

  char* ws = (char*)d_ws;
  float* h5    = (float*)(ws + OFF_H5);
  u16*   upre  = (u16*)  (ws + OFF_UPRE);
  float* lnst  = (float*)(ws + OFF_LNST);
  u16*   eb    = (u16*)  (ws + OFF_E);
  u16*   de    = (u16*)  (ws + OFF_DE);
  float* aggd  = (float*)(ws + OFF_AGG);   // agg (fwd) / dagg (bwd)
  float* dh    = (float*)(ws + OFF_DH);
  float* dist  = (float*)(ws + OFF_DIST);
  float* ddist = (float*)(ws + OFF_DDIST);
  float* dpos  = (float*)(ws + OFF_DPOS);
  float* WmT   = (float*)(ws + OFF_WMT);
  float* WeT   = (float*)(ws + OFF_WET);
  float* WuT   = (float*)(ws + OFF_WUT);

  hipMemsetAsync(ddist, 0, (size_t)NE*4, stream);
  hipMemsetAsync(dpos,  0, (size_t)NN*3*4, stream);
  hipMemsetAsync(de,    0, NEH*2, stream);

  transpose_w<<<512, 256, 0, stream>>>(Wm, We, Wu, WmT, WeT, WuT);
  node_emb<<<NN, 128, 0, stream>>>(x, Wn, bn, h5);
  edge_emb<<<NE/2, 256, 0, stream>>>(ea, We5, be5, eb);
  rel_dist<<<(NE+255)/256, 256, 0, stream>>>(y, ei, dist);

  // ---- forward ----
  for (int l=0; l<NL; l++){
    hipMemsetAsync(aggd, 0, NNH*4, stream);
    efwd<0><<<NE/128, 256, 0, stream>>>(h5 + l*NNH, eb, dist, ei,
        Wm + (size_t)l*385*H, bm + (size_t)l*H, aggd);
    upd_fwd<<<NN, 128, 0, stream>>>(h5 + l*NNH, aggd,
        Wu + (size_t)l*256*H, bu + (size_t)l*H,
        lg + (size_t)l*H, lb + (size_t)l*H,
        upre + l*NNH, lnst + (size_t)l*NN*2, h5 + (l+1)*NNH);
    if (l < NL-1){
      efwd<1><<<NE/128, 256, 0, stream>>>(h5 + (l+1)*NNH, eb, nullptr, ei,
          We + (size_t)l*384*H, beu + (size_t)l*H, nullptr);
    }
  }

  final_fused<<<NN, 128, 0, stream>>>(h5 + (size_t)NL*NNH, Wo, bo, Wh1, bh1v, Wh2, dh);

  // ---- backward ----
  for (int l=NL-1; l>=0; l--){
    if (l < NL-1){
      edge_emb<<<NE/2, 256, 0, stream>>>(ea, We5, be5, eb);
      for (int k=0; k<l; k++){
        efwd<1><<<NE/128, 256, 0, stream>>>(h5 + (k+1)*NNH, eb, nullptr, ei,
            We + (size_t)k*384*H, beu + (size_t)k*H, nullptr);
      }
      ebwd<1><<<NE/128, 256, 0, stream>>>(h5 + (l+1)*NNH, eb, nullptr, ei,
          We + (size_t)l*384*H, beu + (size_t)l*H, nullptr,
          WeT + (size_t)l*128*384, dh, de, nullptr);
    }
    upd_bwd<<<NN, 128, 0, stream>>>(dh, aggd, upre + l*NNH, lnst + (size_t)l*NN*2,
        WuT + (size_t)l*128*256, lg + (size_t)l*H, lb + (size_t)l*H);
    ebwd<0><<<NE/128, 256, 0, stream>>>(h5 + l*NNH, eb, dist, ei,
        Wm + (size_t)l*385*H, bm + (size_t)l*H, aggd,
        WmT + (size_t)l*128*388, dh, de, ddist);
  }

  rel_bwd<<<(NE+255)/256, 256, 0, stream>>>(y, dist, ddist, ei, dpos);
  out_k<<<(NN+255)/256, 256, 0, stream>>>(y, dpos, out);
}

// Round 10
// 26627.020 us; speedup vs baseline: 1.0131x; 1.0131x over previous
//
#include <hip/hip_runtime.h>
#include <hip/hip_bf16.h>

#define NN 20000
#define NE 320000
#define H  128
#define NL 4

typedef unsigned int uint;
typedef unsigned short u16;

static constexpr size_t NNH = (size_t)NN*H;
static constexpr size_t NEH = (size_t)NE*H;

// ---------- workspace layout (bytes), total 261,545,344 ----------
static constexpr size_t OFF_H5    = 0;                                // h5   [5][NN][H] f32
static constexpr size_t OFF_UPRE  = OFF_H5    + 5*NNH*4;              // upre [4][NN][H] bf16
static constexpr size_t OFF_LNST  = OFF_UPRE  + 4*NNH*2;              // lnst [4][NN][2] f32
static constexpr size_t OFF_E     = OFF_LNST  + (size_t)4*NN*2*4;     // e [NE][H] bf16
static constexpr size_t OFF_DE    = OFF_E     + NEH*2;                // de [NE][H] bf16
static constexpr size_t OFF_AGG   = OFF_DE    + NEH*2;                // agg/dagg [NN][H] f32
static constexpr size_t OFF_DH    = OFF_AGG   + NNH*4;                // dh [NN][H] f32
static constexpr size_t OFF_DIST  = OFF_DH    + NNH*4;                // dist [NE] f32
static constexpr size_t OFF_DDIST = OFF_DIST  + (size_t)NE*4;         // ddist [NE] f32
static constexpr size_t OFF_DPOS  = OFF_DDIST + (size_t)NE*4;         // dpos [NN][3] f32
static constexpr size_t OFF_WMT   = OFF_DPOS  + (size_t)NN*3*4;       // WmT [NL][128][388] f32
static constexpr size_t OFF_WET   = OFF_WMT   + (size_t)NL*128*388*4; // WeT [NL][128][384] f32
static constexpr size_t OFF_WUT   = OFF_WET   + (size_t)NL*128*384*4; // WuT [NL][128][256] f32
static constexpr size_t WS_NEED   = OFF_WUT   + (size_t)NL*128*256*4;

// ---------- helpers ----------
__device__ __forceinline__ float sigm(float x){ return 1.f/(1.f+__expf(-x)); }
__device__ __forceinline__ float siluf(float x){ return x*sigm(x); }
__device__ __forceinline__ float dsilu(float x){ float s=sigm(x); return s*(1.f + x*(1.f-s)); }
__device__ __forceinline__ u16 f2bf(float x){
  uint u = __float_as_uint(x);
  uint r = (u + 0x7fffu + ((u>>16)&1u)) >> 16;
  return (u16)r;
}
__device__ __forceinline__ float bf2f(u16 v){ return __uint_as_float(((uint)v)<<16); }
__device__ __forceinline__ uint pack2(float a, float b){ return (uint)f2bf(a) | ((uint)f2bf(b)<<16); }
__device__ __forceinline__ void ld_bf8(const u16* p, float* v){
  uint4 q = *(const uint4*)p;
  v[0]=__uint_as_float(q.x<<16); v[1]=__uint_as_float(q.x&0xffff0000u);
  v[2]=__uint_as_float(q.y<<16); v[3]=__uint_as_float(q.y&0xffff0000u);
  v[4]=__uint_as_float(q.z<<16); v[5]=__uint_as_float(q.z&0xffff0000u);
  v[6]=__uint_as_float(q.w<<16); v[7]=__uint_as_float(q.w&0xffff0000u);
}
__device__ __forceinline__ void st_bf8(u16* p, const float* v){
  uint4 o;
  o.x = pack2(v[0],v[1]); o.y = pack2(v[2],v[3]);
  o.z = pack2(v[4],v[5]); o.w = pack2(v[6],v[7]);
  *(uint4*)p = o;
}

__device__ __forceinline__ float2 blockSum2_128(float a, float b, float* sb){
  #pragma unroll
  for (int off=32; off>0; off>>=1){ a += __shfl_down(a, off); b += __shfl_down(b, off); }
  int t = threadIdx.x;
  if ((t&63)==0){ sb[(t>>6)*2+0]=a; sb[(t>>6)*2+1]=b; }
  __syncthreads();
  float2 r; r.x = sb[0]+sb[2]; r.y = sb[1]+sb[3];
  __syncthreads();
  return r;
}

__global__ void diag_k(float* out, float v){ out[0] = v; }

// ---------- weight transposes ----------
__global__ void transpose_w(const float* __restrict__ Wm, const float* __restrict__ We,
                            const float* __restrict__ Wu,
                            float* __restrict__ WmT, float* __restrict__ WeT,
                            float* __restrict__ WuT){
  int idx = blockIdx.x*blockDim.x + threadIdx.x;
  int stride = gridDim.x*blockDim.x;
  for (int i=idx; i<NL*128*388; i+=stride){
    int l = i/(128*388), r = i - l*128*388, k = r/388, j = r - k*388;
    WmT[i] = (j<385) ? Wm[((size_t)l*385 + j)*H + k] : 0.f;
  }
  for (int i=idx; i<NL*128*384; i+=stride){
    int l = i/(128*384), r = i - l*128*384, k = r/384, j = r - k*384;
    WeT[i] = We[((size_t)l*384 + j)*H + k];
  }
  for (int i=idx; i<NL*128*256; i+=stride){
    int l = i/(128*256), r = i - l*128*256, k = r/256, j = r - k*256;
    WuT[i] = Wu[((size_t)l*256 + j)*H + k];
  }
}

// ---------- small kernels ----------
__global__ __launch_bounds__(128) void node_emb(const float* __restrict__ x,
                                                const float* __restrict__ Wn,
                                                const float* __restrict__ bn,
                                                float* __restrict__ h){
  __shared__ float xs[16];
  int n = blockIdx.x, c = threadIdx.x;
  if (c < 16) xs[c] = x[(size_t)n*16 + c];
  __syncthreads();
  float s = bn[c];
  #pragma unroll
  for (int k=0;k<16;k++) s = fmaf(xs[k], Wn[k*H + c], s);
  h[(size_t)n*H + c] = s;
}

__global__ __launch_bounds__(256) void edge_emb(const float* __restrict__ ea,
                                                const float* __restrict__ We5,
                                                const float* __restrict__ be,
                                                u16* __restrict__ ebuf){
  int e = blockIdx.x*2 + (threadIdx.x>>7);
  int c = threadIdx.x & 127;
  const float* row = ea + (size_t)e*8;
  float v;
  if (c < 3) v = row[c];
  else {
    int j = c-3;
    float s = be[j];
    #pragma unroll
    for (int k=0;k<5;k++) s = fmaf(row[3+k], We5[k*125 + j], s);
    v = s;
  }
  ebuf[(size_t)e*H + c] = f2bf(v);
}

__global__ void rel_dist(const float* __restrict__ y, const int* __restrict__ ei,
                         float* __restrict__ dist){
  int e = blockIdx.x*256 + threadIdx.x;
  if (e >= NE) return;
  int s = ei[e], d = ei[NE+e];
  float rx = y[(size_t)d*6+0] - y[(size_t)s*6+0];
  float ry = y[(size_t)d*6+1] - y[(size_t)s*6+1];
  float rz = y[(size_t)d*6+2] - y[(size_t)s*6+2];
  dist[e] = sqrtf(rx*rx + ry*ry + rz*rz + 1e-8f);
}

// ---------- A-fragment loader (phase-1 gather) ----------
#define LOAD_A(K0, DST) do {                                                      \
    if ((K0) < 256){                                                              \
      const float* _p = hb + (size_t)(((K0)<128)?sidx[srow]:didx[srow])*H + ((K0)&127) + kh; \
      float4 _v0 = *(const float4*)_p, _v1 = *(const float4*)(_p+4);              \
      DST[0]=_v0.x; DST[1]=_v0.y; DST[2]=_v0.z; DST[3]=_v0.w;                     \
      DST[4]=_v1.x; DST[5]=_v1.y; DST[6]=_v1.z; DST[7]=_v1.w;                     \
    } else {                                                                      \
      ld_bf8(eb + (size_t)(e0+srow)*H + ((K0)-256) + kh, DST);                    \
    } } while(0)

#define LOAD_B(SRC, LD, K0, COFF) do {                                            \
    bvn0 = *(const float4*)&(SRC)[(size_t)((K0)+(t>>5))*(LD) + (COFF) + (t&31)*4];      \
    bvn1 = *(const float4*)&(SRC)[(size_t)((K0)+(t>>5)+8)*(LD) + (COFF) + (t&31)*4];    \
  } while(0)

#define COMMIT_AB(BUF) do {                                                       \
    _Pragma("unroll")                                                             \
    for (int _j=0;_j<8;_j++) AstF[BUF][kh+_j][srow] = av[_j];                     \
    *(float4*)&Bs[BUF][t>>5][(t&31)*4]     = bv0;                                 \
    *(float4*)&Bs[BUF][(t>>5)+8][(t&31)*4] = bv1;                                 \
  } while(0)

#define FMA16(BUF, ACC) do {                                                      \
    _Pragma("unroll")                                                             \
    for (int kk=0;kk<16;kk++){                                                    \
      float4 a0 = *(const float4*)&AstF[BUF][kk][r0];                             \
      float4 a1 = *(const float4*)&AstF[BUF][kk][r0+4];                           \
      float4 b0 = *(const float4*)&Bs[BUF][kk][c0];                               \
      float4 b1 = *(const float4*)&Bs[BUF][kk][c0+4];                             \
      float _av[8] = {a0.x,a0.y,a0.z,a0.w,a1.x,a1.y,a1.z,a1.w};                   \
      float _bv[8] = {b0.x,b0.y,b0.z,b0.w,b1.x,b1.y,b1.z,b1.w};                   \
      _Pragma("unroll")                                                           \
      for (int _r=0;_r<8;_r++){                                                   \
        _Pragma("unroll")                                                         \
        for (int _c=0;_c<8;_c++) ACC[_r][_c] = fmaf(_av[_r], _bv[_c], ACC[_r][_c]); \
      }                                                                           \
    } } while(0)

// ---------- edge GEMM forward (MODE 0 = msg->agg, 1 = eu e+=silu in-place) ----------
template<int MODE>
__global__ __launch_bounds__(256) void efwd(
    const float* __restrict__ hb, u16* __restrict__ eb,
    const float* __restrict__ dist, const int* __restrict__ ei,
    const float* __restrict__ W, const float* __restrict__ bias,
    float* __restrict__ agg)
{
  __shared__ __align__(16) float AstF[2][16][128];
  __shared__ __align__(16) float Bs[2][16][128];
  __shared__ int sidx[128], didx[128];
  const int t = threadIdx.x;
  const int e0 = blockIdx.x * 128;
  if (t < 128){ sidx[t] = ei[e0+t]; didx[t] = ei[NE+e0+t]; }
  __syncthreads();
  float acc[8][8];
  #pragma unroll
  for (int i=0;i<8;i++){
    #pragma unroll
    for (int j=0;j<8;j++) acc[i][j]=0.f;
  }
  const int srow = t>>1, kh = (t&1)*8;
  const int r0 = (t>>4)*8, c0 = (t&15)*8;

  float av[8], avn[8];
  float4 bv0, bv1, bvn0, bvn1;
  LOAD_A(0, avn); LOAD_B(W, H, 0, 0);
  int cur = 0;
  #pragma unroll 1
  for (int k0=0; k0<384; k0+=16){
    #pragma unroll
    for (int j=0;j<8;j++) av[j] = avn[j];
    bv0 = bvn0; bv1 = bvn1;
    COMMIT_AB(cur);
    __syncthreads();
    if (k0+16 < 384){ LOAD_A(k0+16, avn); LOAD_B(W, H, k0+16, 0); }
    FMA16(cur, acc);
    cur ^= 1;
  }

  float bi[8];
  { float4 x0 = *(const float4*)&bias[c0]; float4 x1 = *(const float4*)&bias[c0+4];
    bi[0]=x0.x;bi[1]=x0.y;bi[2]=x0.z;bi[3]=x0.w;bi[4]=x1.x;bi[5]=x1.y;bi[6]=x1.z;bi[7]=x1.w; }
  if (MODE==0){
    float wd[8];
    float4 y0=*(const float4*)&W[(size_t)384*H + c0];
    float4 y1=*(const float4*)&W[(size_t)384*H + c0+4];
    wd[0]=y0.x;wd[1]=y0.y;wd[2]=y0.z;wd[3]=y0.w;wd[4]=y1.x;wd[5]=y1.y;wd[6]=y1.z;wd[7]=y1.w;
    #pragma unroll
    for (int r=0;r<8;r++){
      int eidx = e0 + r0 + r;
      float dv = dist[eidx];
      int dn = didx[r0+r];
      #pragma unroll
      for (int c=0;c<8;c++){
        float v = acc[r][c] + bi[c] + dv*wd[c];
        atomicAdd(&agg[(size_t)dn*H + c0 + c], siluf(v));
      }
    }
  } else {
    #pragma unroll
    for (int r=0;r<8;r++){
      u16* ep = eb + (size_t)(e0 + r0 + r)*H + c0;
      float ev[8]; ld_bf8(ep, ev);
      #pragma unroll
      for (int c=0;c<8;c++) ev[c] += siluf(acc[r][c]+bi[c]);
      st_bf8(ep, ev);
    }
  }
}

// ---------- fused edge backward ----------
// phase1: pre = [h_s,h_d,e(,dist)]@W + b  (f32, reg-prefetched)
// phase2: A = mul*dsilu(pre) in regs; pdist via shfl reduce (exact f32)
// stage:  A^T -> LDS bf16, XOR-swizzled, once
// phase3: 3x GEMM A@WT chunks, Bs double-buffered, 1 barrier/chunk
template<int MODE>
__global__ __launch_bounds__(256) void ebwd(
    const float* __restrict__ hb, const u16* __restrict__ eb,
    const float* __restrict__ dist, const int* __restrict__ ei,
    const float* __restrict__ W, const float* __restrict__ bias,
    const float* __restrict__ mulf, const float* __restrict__ WT,
    float* __restrict__ dh, u16* __restrict__ de, float* __restrict__ ddist)
{
  const int ldB = (MODE==0) ? 388 : 384;
  __shared__ __align__(16) u16 Au16[128*128];          // 32KB; first 16KB doubles as AstF
  __shared__ __align__(16) float Bs[2][16][128];       // 16KB
  __shared__ int sidx[128], didx[128];
  float (*AstF)[16][128] = (float(*)[16][128])Au16;
  const int t = threadIdx.x;
  const int e0 = blockIdx.x * 128;
  if (t < 128){ sidx[t] = ei[e0+t]; didx[t] = ei[NE+e0+t]; }
  __syncthreads();
  const int srow = t>>1, kh = (t&1)*8;
  const int r0 = (t>>4)*8, c0 = (t&15)*8;
  const int tq = t>>4, t15 = t&15;

  // ---- phase 1 ----
  float pre[8][8];
  #pragma unroll
  for (int i=0;i<8;i++){
    #pragma unroll
    for (int j=0;j<8;j++) pre[i][j]=0.f;
  }
  {
    float av[8], avn[8];
    float4 bv0, bv1, bvn0, bvn1;
    LOAD_A(0, avn); LOAD_B(W, H, 0, 0);
    int cur = 0;
    #pragma unroll 1
    for (int k0=0; k0<384; k0+=16){
      #pragma unroll
      for (int j=0;j<8;j++) av[j] = avn[j];
      bv0 = bvn0; bv1 = bvn1;
      COMMIT_AB(cur);
      __syncthreads();
      if (k0+16 < 384){ LOAD_A(k0+16, avn); LOAD_B(W, H, k0+16, 0); }
      FMA16(cur, pre);
      cur ^= 1;
    }
  }
  {
    float bi[8];
    float4 x0 = *(const float4*)&bias[c0]; float4 x1 = *(const float4*)&bias[c0+4];
    bi[0]=x0.x;bi[1]=x0.y;bi[2]=x0.z;bi[3]=x0.w;bi[4]=x1.x;bi[5]=x1.y;bi[6]=x1.z;bi[7]=x1.w;
    float wd[8] = {0,0,0,0,0,0,0,0};
    if (MODE==0){
      float4 y0=*(const float4*)&W[(size_t)384*H + c0];
      float4 y1=*(const float4*)&W[(size_t)384*H + c0+4];
      wd[0]=y0.x;wd[1]=y0.y;wd[2]=y0.z;wd[3]=y0.w;wd[4]=y1.x;wd[5]=y1.y;wd[6]=y1.z;wd[7]=y1.w;
    }
    #pragma unroll
    for (int r=0;r<8;r++){
      float dv = (MODE==0) ? dist[e0+r0+r] : 0.f;
      #pragma unroll
      for (int c=0;c<8;c++) pre[r][c] += bi[c] + dv*wd[c];
    }
  }

  // ---- phase 2: A = mul*dsilu(pre) ----
  #pragma unroll
  for (int r=0;r<8;r++){
    float mv[8];
    if (MODE==0){
      const float* mp = mulf + (size_t)didx[r0+r]*H + c0;
      float4 m0 = *(const float4*)mp, m1 = *(const float4*)(mp+4);
      mv[0]=m0.x;mv[1]=m0.y;mv[2]=m0.z;mv[3]=m0.w;mv[4]=m1.x;mv[5]=m1.y;mv[6]=m1.z;mv[7]=m1.w;
    } else {
      ld_bf8(de + (size_t)(e0+r0+r)*H + c0, mv);
    }
    #pragma unroll
    for (int c=0;c<8;c++) pre[r][c] = mv[c]*dsilu(pre[r][c]);
  }

  // ---- pdist (MODE 0): exact f32 A, shfl-reduce over the 16 col-groups ----
  if (MODE==0){
    float wdist[8];
    #pragma unroll
    for (int j=0;j<8;j++) wdist[j] = WT[(size_t)(c0+j)*388 + 384];
    #pragma unroll
    for (int r=0;r<8;r++){
      float pd = 0.f;
      #pragma unroll
      for (int j=0;j<8;j++) pd = fmaf(pre[r][j], wdist[j], pd);
      pd += __shfl_xor(pd, 1);
      pd += __shfl_xor(pd, 2);
      pd += __shfl_xor(pd, 4);
      pd += __shfl_xor(pd, 8);
      if (t15 == 0) ddist[e0 + r0 + r] += pd;
    }
  }

  // ---- stage A^T (bf16, swizzled) ----
  __syncthreads();   // phase-1 LDS reads complete before overwriting AstF region
  #pragma unroll
  for (int j=0;j<8;j++){
    uint4 q;
    q.x = pack2(pre[0][j], pre[1][j]);
    q.y = pack2(pre[2][j], pre[3][j]);
    q.z = pack2(pre[4][j], pre[5][j]);
    q.w = pack2(pre[6][j], pre[7][j]);
    *(uint4*)&Au16[(size_t)(c0+j)*128 + ((tq ^ t15) & 15)*8] = q;
  }
  __syncthreads();

  // ---- phase 3: 3 GEMMs, Bs double-buffered ----
  float4 bvn0, bvn1;
  LOAD_B(WT, ldB, 0, 0);
  int cur = 0;
  #pragma unroll 1
  for (int jc=0; jc<3; jc++){
    float acc[8][8];
    #pragma unroll
    for (int i=0;i<8;i++){
      #pragma unroll
      for (int j=0;j<8;j++) acc[i][j]=0.f;
    }
    #pragma unroll 1
    for (int k0=0; k0<128; k0+=16){
      *(float4*)&Bs[cur][t>>5][(t&31)*4]     = bvn0;
      *(float4*)&Bs[cur][(t>>5)+8][(t&31)*4] = bvn1;
      __syncthreads();
      { int njc = jc, nk0 = k0+16;
        if (nk0 == 128){ njc = jc+1; nk0 = 0; }
        if (njc < 3) LOAD_B(WT, ldB, nk0, njc*128); }
      #pragma unroll
      for (int kk=0;kk<16;kk++){
        int ka = k0 + kk;
        float avv[8];
        ld_bf8(&Au16[(size_t)ka*128 + ((tq ^ ((ka>>3)&15)) & 15)*8], avv);
        float4 b0 = *(const float4*)&Bs[cur][kk][c0];
        float4 b1 = *(const float4*)&Bs[cur][kk][c0+4];
        float bvv[8] = {b0.x,b0.y,b0.z,b0.w,b1.x,b1.y,b1.z,b1.w};
        #pragma unroll
        for (int r=0;r<8;r++){
          #pragma unroll
          for (int c=0;c<8;c++) acc[r][c] = fmaf(avv[r], bvv[c], acc[r][c]);
        }
      }
      cur ^= 1;
    }
    if (jc==0){
      #pragma unroll
      for (int r=0;r<8;r++){
        int sn = sidx[r0+r];
        #pragma unroll
        for (int c=0;c<8;c++) atomicAdd(&dh[(size_t)sn*H + c0 + c], acc[r][c]);
      }
    } else if (jc==1){
      #pragma unroll
      for (int r=0;r<8;r++){
        int dn = didx[r0+r];
        #pragma unroll
        for (int c=0;c<8;c++) atomicAdd(&dh[(size_t)dn*H + c0 + c], acc[r][c]);
      }
    } else {
      #pragma unroll
      for (int r=0;r<8;r++){
        u16* ep = de + (size_t)(e0+r0+r)*H + c0;
        float ev[8]; ld_bf8(ep, ev);
        #pragma unroll
        for (int c=0;c<8;c++) ev[c] += acc[r][c];
        st_bf8(ep, ev);
      }
    }
  }
}

// ---------- node update forward ----------
__global__ __launch_bounds__(128) void upd_fwd(
    const float* __restrict__ hin, const float* __restrict__ agg,
    const float* __restrict__ Wu, const float* __restrict__ bu,
    const float* __restrict__ g, const float* __restrict__ bln,
    u16* __restrict__ upre, float* __restrict__ lnst, float* __restrict__ hout)
{
  __shared__ float ha[256];
  __shared__ float sb[4];
  int n = blockIdx.x, c = threadIdx.x;
  float hv = hin[(size_t)n*H + c];
  ha[c] = hv;
  ha[128+c] = agg[(size_t)n*H + c];
  __syncthreads();
  float s = bu[c];
  #pragma unroll 4
  for (int k=0;k<256;k++) s = fmaf(ha[k], Wu[(size_t)k*H + c], s);
  upre[(size_t)n*H + c] = f2bf(s);
  float2 ms = blockSum2_128(s, s*s, sb);
  float mu = ms.x*(1.f/128.f);
  float var = ms.y*(1.f/128.f) - mu*mu;
  float rstd = rsqrtf(var + 1e-5f);
  if (c == 0){ lnst[(size_t)n*2+0] = mu; lnst[(size_t)n*2+1] = rstd; }
  float uh = (s - mu)*rstd;
  float un = uh*g[c] + bln[c];
  hout[(size_t)n*H + c] = hv + siluf(un);
}

// ---------- final MLP fused fwd+bwd -> dh ----------
__global__ __launch_bounds__(128) void final_fused(
    const float* __restrict__ h, const float* __restrict__ Wo, const float* __restrict__ bo,
    const float* __restrict__ Wh1, const float* __restrict__ bh1v,
    const float* __restrict__ Wh2, float* __restrict__ dh)
{
  __shared__ float sh[128], sf[64], sdz[32], sdf[64];
  int n = blockIdx.x, c = threadIdx.x;
  sh[c] = h[(size_t)n*H + c];
  __syncthreads();
  if (c < 64){
    float s = bo[c];
    #pragma unroll 4
    for (int k=0;k<128;k++) s = fmaf(sh[k], Wo[(size_t)k*64 + c], s);
    sf[c] = s;
  }
  __syncthreads();
  if (c < 32){
    float s = bh1v[c];
    #pragma unroll 4
    for (int j=0;j<64;j++) s = fmaf(sf[j], Wh1[(size_t)j*32 + c], s);
    sdz[c] = Wh2[c]*dsilu(s);
  }
  __syncthreads();
  if (c < 64){
    float s = 0.f;
    #pragma unroll 4
    for (int k=0;k<32;k++) s = fmaf(sdz[k], Wh1[(size_t)c*32 + k], s);
    sdf[c] = s;
  }
  __syncthreads();
  {
    float s = 0.f;
    #pragma unroll 4
    for (int j=0;j<64;j++) s = fmaf(sdf[j], Wo[(size_t)c*64 + j], s);
    dh[(size_t)n*H + c] = s;
  }
}

// ---------- node update backward ----------
__global__ __launch_bounds__(128) void upd_bwd(
    float* __restrict__ dh, float* __restrict__ dagg,
    const u16* __restrict__ upre, const float* __restrict__ lnst,
    const float* __restrict__ WuT,
    const float* __restrict__ g, const float* __restrict__ bln)
{
  __shared__ float sh[128];
  __shared__ float sb[4];
  int n = blockIdx.x, c = threadIdx.x;
  float up   = bf2f(upre[(size_t)n*H + c]);
  float mu   = lnst[(size_t)n*2+0];
  float rstd = lnst[(size_t)n*2+1];
  float uh = (up - mu)*rstd;
  float un = uh*g[c] + bln[c];
  float dhv = dh[(size_t)n*H + c];
  float dun = dhv * dsilu(un);
  float duh = dun * g[c];
  float2 m12 = blockSum2_128(duh, duh*uh, sb);
  float m1 = m12.x*(1.f/128.f), m2 = m12.y*(1.f/128.f);
  float dup = (duh - m1 - uh*m2)*rstd;
  sh[c] = dup;
  __syncthreads();
  float s0 = 0.f, s1 = 0.f;
  #pragma unroll 4
  for (int k=0;k<128;k++){
    float d = sh[k];
    s0 = fmaf(d, WuT[(size_t)k*256 + c], s0);
    s1 = fmaf(d, WuT[(size_t)k*256 + 128 + c], s1);
  }
  dh[(size_t)n*H + c] = dhv + s0;
  dagg[(size_t)n*H + c] = s1;
}

// ---------- dist -> dpos ----------
__global__ void rel_bwd(const float* __restrict__ y, const float* __restrict__ dist,
                        const float* __restrict__ ddist, const int* __restrict__ ei,
                        float* __restrict__ dpos){
  int e = blockIdx.x*256 + threadIdx.x;
  if (e >= NE) return;
  int s = ei[e], d = ei[NE+e];
  float gsc = ddist[e]/dist[e];
  #pragma unroll
  for (int i=0;i<3;i++){
    float dr = gsc*(y[(size_t)d*6+i] - y[(size_t)s*6+i]);
    atomicAdd(&dpos[(size_t)d*3+i],  dr);
    atomicAdd(&dpos[(size_t)s*3+i], -dr);
  }
}

// ---------- output (f32) ----------
__global__ void out_k(const float* __restrict__ y, const float* __restrict__ dpos,
                      float* __restrict__ out){
  int n = blockIdx.x*256 + threadIdx.x;
  if (n >= NN) return;
  #pragma unroll
  for (int i=0;i<3;i++) out[(size_t)n*6+i]   =  y[(size_t)n*6+3+i];
  #pragma unroll
  for (int i=0;i<3;i++) out[(size_t)n*6+3+i] = -dpos[(size_t)n*3+i];
}

// ---------- host ----------
extern "C" void kernel_launch(void* const* d_in, const int* in_sizes, int n_in,
                              void* d_out, int out_size, void* d_ws, size_t ws_size,
                              hipStream_t stream)
{
  const float* y   = (const float*)d_in[0];
  const float* x   = (const float*)d_in[1];
  const float* ea  = (const float*)d_in[2];
  const int*   ei  = (const int*)d_in[3];
  const float* Wn  = (const float*)d_in[4];
  const float* bn  = (const float*)d_in[5];
  const float* We5 = (const float*)d_in[6];
  const float* be5 = (const float*)d_in[7];
  const float* Wm  = (const float*)d_in[8];
  const float* bm  = (const float*)d_in[9];
  const float* Wu  = (const float*)d_in[10];
  const float* bu  = (const float*)d_in[11];
  const float* lg  = (const float*)d_in[12];
  const float* lb  = (const float*)d_in[13];
  const float* We  = (const float*)d_in[14];
  const float* beu = (const float*)d_in[15];
  const float* Wo  = (const float*)d_in[16];
  const float* bo  = (const float*)d_in[17];
  const float* Wh1 = (const float*)d_in[18];
  const float* bh1v= (const float*)d_in[19];
  const float* Wh2 = (const float*)d_in[20];
  float* out = (float*)d_out;

  if (ws_size < WS_NEED){
    diag_k<<<1, 1, 0, stream>>>(out, 4000.f + (float)(ws_size >> 20));
    return;
  }

  char* ws = (char*)d_ws;
  float* h5    = (float*)(ws + OFF_H5);
  u16*   upre  = (u16*)  (ws + OFF_UPRE);
  float* lnst  = (float*)(ws + OFF_LNST);
  u16*   eb    = (u16*)  (ws + OFF_E);
  u16*   de    = (u16*)  (ws + OFF_DE);
  float* aggd  = (float*)(ws + OFF_AGG);
  float* dh    = (float*)(ws + OFF_DH);
  float* dist  = (float*)(ws + OFF_DIST);
  float* ddist = (float*)(ws + OFF_DDIST);
  float* dpos  = (float*)(ws + OFF_DPOS);
  float* WmT   = (float*)(ws + OFF_WMT);
  float* WeT   = (float*)(ws + OFF_WET);
  float* WuT   = (float*)(ws + OFF_WUT);

  hipMemsetAsync(ddist, 0, (size_t)NE*4, stream);
  hipMemsetAsync(dpos,  0, (size_t)NN*3*4, stream);
  hipMemsetAsync(de,    0, NEH*2, stream);

  transpose_w<<<512, 256, 0, stream>>>(Wm, We, Wu, WmT, WeT, WuT);
  node_emb<<<NN, 128, 0, stream>>>(x, Wn, bn, h5);
  edge_emb<<<NE/2, 256, 0, stream>>>(ea, We5, be5, eb);
  rel_dist<<<(NE+255)/256, 256, 0, stream>>>(y, ei, dist);

  // ---- forward ----
  for (int l=0; l<NL; l++){
    hipMemsetAsync(aggd, 0, NNH*4, stream);
    efwd<0><<<NE/128, 256, 0, stream>>>(h5 + l*NNH, eb, dist, ei,
        Wm + (size_t)l*385*H, bm + (size_t)l*H, aggd);
    upd_fwd<<<NN, 128, 0, stream>>>(h5 + l*NNH, aggd,
        Wu + (size_t)l*256*H, bu + (size_t)l*H,
        lg + (size_t)l*H, lb + (size_t)l*H,
        upre + l*NNH, lnst + (size_t)l*NN*2, h5 + (l+1)*NNH);
    if (l < NL-1){
      efwd<1><<<NE/128, 256, 0, stream>>>(h5 + (l+1)*NNH, eb, nullptr, ei,
          We + (size_t)l*384*H, beu + (size_t)l*H, nullptr);
    }
  }

  final_fused<<<NN, 128, 0, stream>>>(h5 + (size_t)NL*NNH, Wo, bo, Wh1, bh1v, Wh2, dh);

  // ---- backward ----
  for (int l=NL-1; l>=0; l--){
    if (l < NL-1){
      edge_emb<<<NE/2, 256, 0, stream>>>(ea, We5, be5, eb);
      for (int k=0; k<l; k++){
        efwd<1><<<NE/128, 256, 0, stream>>>(h5 + (k+1)*NNH, eb, nullptr, ei,
            We + (size_t)k*384*H, beu + (size_t)k*H, nullptr);
      }
      ebwd<1><<<NE/128, 256, 0, stream>>>(h5 + (l+1)*NNH, eb, nullptr, ei,
          We + (size_t)l*384*H, beu + (size_t)l*H, nullptr,
          WeT + (size_t)l*128*384, dh, de, nullptr);
    }
    upd_bwd<<<NN, 128, 0, stream>>>(dh, aggd, upre + l*NNH, lnst + (size_t)l*NN*2,
        WuT + (size_t)l*128*256, lg + (size_t)l*H, lb + (size_t)l*H);
    ebwd<0><<<NE/128, 256, 0, stream>>>(h5 + l*NNH, eb, dist, ei,
        Wm + (size_t)l*385*H, bm + (size_t)l*H, aggd,
        WmT + (size_t)l*128*388, dh, de, ddist);
  }

  rel_bwd<<<(NE+255)/256, 256, 0, stream>>>(y, dist, ddist, ei, dpos);
  out_k<<<(NN+255)/256, 256, 0, stream>>>(y, dpos, out);
}

// Round 11
// 15447.467 us; speedup vs baseline: 1.7463x; 1.7237x over previous
//
#include <hip/hip_runtime.h>
#include <hip/hip_bf16.h>

#define NN 20000
#define NE 320000
#define H  128
#define NL 4

typedef unsigned int uint;
typedef unsigned short u16;

static constexpr size_t NNH = (size_t)NN*H;
static constexpr size_t NEH = (size_t)NE*H;

// ---------- workspace layout (bytes), total 259,145,344 (proven ws >= 261,545,344) ----------
static constexpr size_t OFF_H5    = 0;                                // h5   [5][NN][H] bf16
static constexpr size_t OFF_UPRE  = OFF_H5    + 5*NNH*2;              // upre [4][NN][H] bf16
static constexpr size_t OFF_LNST  = OFF_UPRE  + 4*NNH*2;              // lnst [4][NN][2] f32
static constexpr size_t OFF_T     = OFF_LNST  + (size_t)4*NN*2*4;     // T [4][NN][H] bf16 (dsilu sums)
static constexpr size_t OFF_E     = OFF_T     + 4*NNH*2;              // e [NE][H] bf16
static constexpr size_t OFF_DE    = OFF_E     + NEH*2;                // de [NE][H] bf16
static constexpr size_t OFF_AGG   = OFF_DE    + NEH*2;                // agg/dagg [NN][H] f32
static constexpr size_t OFF_DH    = OFF_AGG   + NNH*4;                // dh [NN][H] f32 (Tf in fwd)
static constexpr size_t OFF_DIST  = OFF_DH    + NNH*4;                // dist [NE] f32
static constexpr size_t OFF_DDIST = OFF_DIST  + (size_t)NE*4;         // ddist [NE] f32
static constexpr size_t OFF_DPOS  = OFF_DDIST + (size_t)NE*4;         // dpos [NN][3] f32
static constexpr size_t OFF_WMT   = OFF_DPOS  + (size_t)NN*3*4;       // WmT [NL][128][388] f32
static constexpr size_t OFF_WET   = OFF_WMT   + (size_t)NL*128*388*4; // WeT [NL][128][384] f32
static constexpr size_t OFF_WUT   = OFF_WET   + (size_t)NL*128*384*4; // WuT [NL][128][256] f32
static constexpr size_t OFF_PD    = OFF_WUT   + (size_t)NL*128*256*4; // perm_d [NE] int
static constexpr size_t OFF_PS    = OFF_PD    + (size_t)NE*4;         // perm_s [NE] int
static constexpr size_t OFF_CURD  = OFF_PS    + (size_t)NE*4;         // curd [NN] int
static constexpr size_t OFF_CURS  = OFF_CURD  + (size_t)NN*4;         // curs [NN] int
static constexpr size_t WS_NEED   = OFF_CURS  + (size_t)NN*4;

// ---------- helpers ----------
__device__ __forceinline__ float sigm(float x){ return 1.f/(1.f+__expf(-x)); }
__device__ __forceinline__ float siluf(float x){ return x*sigm(x); }
__device__ __forceinline__ float dsilu(float x){ float s=sigm(x); return s*(1.f + x*(1.f-s)); }
__device__ __forceinline__ u16 f2bf(float x){
  uint u = __float_as_uint(x);
  uint r = (u + 0x7fffu + ((u>>16)&1u)) >> 16;
  return (u16)r;
}
__device__ __forceinline__ float bf2f(u16 v){ return __uint_as_float(((uint)v)<<16); }
__device__ __forceinline__ uint pack2(float a, float b){ return (uint)f2bf(a) | ((uint)f2bf(b)<<16); }
__device__ __forceinline__ void ld_bf8(const u16* p, float* v){
  uint4 q = *(const uint4*)p;
  v[0]=__uint_as_float(q.x<<16); v[1]=__uint_as_float(q.x&0xffff0000u);
  v[2]=__uint_as_float(q.y<<16); v[3]=__uint_as_float(q.y&0xffff0000u);
  v[4]=__uint_as_float(q.z<<16); v[5]=__uint_as_float(q.z&0xffff0000u);
  v[6]=__uint_as_float(q.w<<16); v[7]=__uint_as_float(q.w&0xffff0000u);
}
__device__ __forceinline__ void st_bf8(u16* p, const float* v){
  uint4 o;
  o.x = pack2(v[0],v[1]); o.y = pack2(v[2],v[3]);
  o.z = pack2(v[4],v[5]); o.w = pack2(v[6],v[7]);
  *(uint4*)p = o;
}

__device__ __forceinline__ float2 blockSum2_128(float a, float b, float* sb){
  #pragma unroll
  for (int off=32; off>0; off>>=1){ a += __shfl_down(a, off); b += __shfl_down(b, off); }
  int t = threadIdx.x;
  if ((t&63)==0){ sb[(t>>6)*2+0]=a; sb[(t>>6)*2+1]=b; }
  __syncthreads();
  float2 r; r.x = sb[0]+sb[2]; r.y = sb[1]+sb[3];
  __syncthreads();
  return r;
}

// segment-reduce staged rows (Cst [128 rows][128 cols] bf16, plain layout) by LDS keys.
// 256 threads: col = t&127, half = t>>7 -> rows half*64..+63. Boundary atomics only.
__device__ __forceinline__ void seg_walk(const u16* Cst, const int* keys, float* buf, int t){
  int c = t & 127, half = t >> 7;
  int i0 = half*64, i1 = i0 + 64;
  float acc = 0.f; int k = keys[i0];
  #pragma unroll 4
  for (int i=i0; i<i1; i++){
    int ki = keys[i];
    if (ki != k){ atomicAdd(&buf[(size_t)k*H + c], acc); acc = 0.f; k = ki; }
    acc += bf2f(Cst[(size_t)i*128 + c]);
  }
  atomicAdd(&buf[(size_t)k*H + c], acc);
}

__global__ void diag_k(float* out, float v){ out[0] = v; }

// ---------- sort construction ----------
__global__ void hist_k(const int* __restrict__ ei, int* __restrict__ curs, int* __restrict__ curd){
  int e = blockIdx.x*256 + threadIdx.x;
  if (e >= NE) return;
  atomicAdd(&curs[ei[e]], 1);
  atomicAdd(&curd[ei[NE+e]], 1);
}

__global__ void scan_k(int* __restrict__ curd, int* __restrict__ curs){
  __shared__ int sm[256];
  for (int a=0; a<2; a++){
    int* p = a ? curs : curd;
    int run = 0;
    for (int base=0; base<NN; base+=256){
      int idx = base + threadIdx.x;
      sm[threadIdx.x] = (idx < NN) ? p[idx] : 0;
      __syncthreads();
      if (threadIdx.x == 0){
        int acc = run;
        for (int i=0;i<256;i++){ int v = sm[i]; sm[i] = acc; acc += v; }
        run = acc;
      }
      __syncthreads();
      if (idx < NN) p[idx] = sm[threadIdx.x];
      __syncthreads();
    }
  }
}

__global__ void fill_k(const int* __restrict__ ei, int* __restrict__ curs, int* __restrict__ curd,
                       int* __restrict__ perm_s, int* __restrict__ perm_d){
  int e = blockIdx.x*256 + threadIdx.x;
  if (e >= NE) return;
  perm_s[atomicAdd(&curs[ei[e]], 1)] = e;
  perm_d[atomicAdd(&curd[ei[NE+e]], 1)] = e;
}

// ---------- weight transposes ----------
__global__ void transpose_w(const float* __restrict__ Wm, const float* __restrict__ We,
                            const float* __restrict__ Wu,
                            float* __restrict__ WmT, float* __restrict__ WeT,
                            float* __restrict__ WuT){
  int idx = blockIdx.x*blockDim.x + threadIdx.x;
  int stride = gridDim.x*blockDim.x;
  for (int i=idx; i<NL*128*388; i+=stride){
    int l = i/(128*388), r = i - l*128*388, k = r/388, j = r - k*388;
    WmT[i] = (j<385) ? Wm[((size_t)l*385 + j)*H + k] : 0.f;
  }
  for (int i=idx; i<NL*128*384; i+=stride){
    int l = i/(128*384), r = i - l*128*384, k = r/384, j = r - k*384;
    WeT[i] = We[((size_t)l*384 + j)*H + k];
  }
  for (int i=idx; i<NL*128*256; i+=stride){
    int l = i/(128*256), r = i - l*128*256, k = r/256, j = r - k*256;
    WuT[i] = Wu[((size_t)l*256 + j)*H + k];
  }
}

// ---------- small kernels ----------
__global__ __launch_bounds__(128) void node_emb(const float* __restrict__ x,
                                                const float* __restrict__ Wn,
                                                const float* __restrict__ bn,
                                                u16* __restrict__ h){
  __shared__ float xs[16];
  int n = blockIdx.x, c = threadIdx.x;
  if (c < 16) xs[c] = x[(size_t)n*16 + c];
  __syncthreads();
  float s = bn[c];
  #pragma unroll
  for (int k=0;k<16;k++) s = fmaf(xs[k], Wn[k*H + c], s);
  h[(size_t)n*H + c] = f2bf(s);
}

__global__ __launch_bounds__(256) void edge_emb(const float* __restrict__ ea,
                                                const float* __restrict__ We5,
                                                const float* __restrict__ be,
                                                u16* __restrict__ ebuf){
  int e = blockIdx.x*2 + (threadIdx.x>>7);
  int c = threadIdx.x & 127;
  const float* row = ea + (size_t)e*8;
  float v;
  if (c < 3) v = row[c];
  else {
    int j = c-3;
    float s = be[j];
    #pragma unroll
    for (int k=0;k<5;k++) s = fmaf(row[3+k], We5[k*125 + j], s);
    v = s;
  }
  ebuf[(size_t)e*H + c] = f2bf(v);
}

__global__ void rel_dist(const float* __restrict__ y, const int* __restrict__ ei,
                         float* __restrict__ dist){
  int e = blockIdx.x*256 + threadIdx.x;
  if (e >= NE) return;
  int s = ei[e], d = ei[NE+e];
  float rx = y[(size_t)d*6+0] - y[(size_t)s*6+0];
  float ry = y[(size_t)d*6+1] - y[(size_t)s*6+1];
  float rz = y[(size_t)d*6+2] - y[(size_t)s*6+2];
  dist[e] = sqrtf(rx*rx + ry*ry + rz*rz + 1e-8f);
}

// ---------- shared GEMM macros ----------
#define LOAD_A(K0, DST) do {                                                      \
    const u16* _p;                                                                \
    if ((K0) < 128)      _p = hb + (size_t)sidx[srow]*H + (K0) + kh;              \
    else if ((K0) < 256) _p = hb + (size_t)didx[srow]*H + ((K0)-128) + kh;        \
    else                 _p = eb + (size_t)eidl[srow]*H + ((K0)-256) + kh;        \
    ld_bf8(_p, DST); } while(0)

#define LOAD_B(SRC, LD, K0, COFF) do {                                            \
    bvn0 = *(const float4*)&(SRC)[(size_t)((K0)+(t>>5))*(LD) + (COFF) + (t&31)*4];      \
    bvn1 = *(const float4*)&(SRC)[(size_t)((K0)+(t>>5)+8)*(LD) + (COFF) + (t&31)*4];    \
  } while(0)

#define COMMIT_AB(BUF) do {                                                       \
    _Pragma("unroll")                                                             \
    for (int _j=0;_j<8;_j++) AstF[BUF][kh+_j][srow] = av[_j];                     \
    *(float4*)&Bs[BUF][t>>5][(t&31)*4]     = bv0;                                 \
    *(float4*)&Bs[BUF][(t>>5)+8][(t&31)*4] = bv1;                                 \
  } while(0)

#define FMA16(BUF, ACC) do {                                                      \
    _Pragma("unroll")                                                             \
    for (int kk=0;kk<16;kk++){                                                    \
      float4 a0 = *(const float4*)&AstF[BUF][kk][r0];                             \
      float4 a1 = *(const float4*)&AstF[BUF][kk][r0+4];                           \
      float4 b0 = *(const float4*)&Bs[BUF][kk][c0];                               \
      float4 b1 = *(const float4*)&Bs[BUF][kk][c0+4];                             \
      float _av[8] = {a0.x,a0.y,a0.z,a0.w,a1.x,a1.y,a1.z,a1.w};                   \
      float _bv[8] = {b0.x,b0.y,b0.z,b0.w,b1.x,b1.y,b1.z,b1.w};                   \
      _Pragma("unroll")                                                           \
      for (int _r=0;_r<8;_r++){                                                   \
        _Pragma("unroll")                                                         \
        for (int _c=0;_c<8;_c++) ACC[_r][_c] = fmaf(_av[_r], _bv[_c], ACC[_r][_c]); \
      }                                                                           \
    } } while(0)

// ---------- edge GEMM forward ----------
// MODE 0: msg, dst-sorted (perm); epilogue: seg-reduce silu->agg and dsilu->Tf (both keyed by dst)
// MODE 1: eu, natural order (perm=null); epilogue: e += silu (in-place rows)
template<int MODE>
__global__ __launch_bounds__(256) void efwd(
    const u16* __restrict__ hb, u16* __restrict__ eb,
    const float* __restrict__ dist, const int* __restrict__ ei,
    const int* __restrict__ perm,
    const float* __restrict__ W, const float* __restrict__ bias,
    float* __restrict__ agg, float* __restrict__ Tf)
{
  __shared__ __align__(16) char smem[32768];   // AstF[2]+Bs[2] (GEMM) then Cst overlay (MODE 0)
  float (*AstF)[16][128] = (float(*)[16][128])smem;
  float (*Bs)[16][128]   = (float(*)[16][128])(smem + 16384);
  u16* Cst = (u16*)smem;
  __shared__ int eidl[128], sidx[128], didx[128];
  const int t = threadIdx.x;
  const int e0 = blockIdx.x * 128;
  if (t < 128){
    int eid = perm ? perm[e0+t] : (e0+t);
    eidl[t] = eid; sidx[t] = ei[eid]; didx[t] = ei[NE+eid];
  }
  __syncthreads();
  float acc[8][8];
  #pragma unroll
  for (int i=0;i<8;i++){
    #pragma unroll
    for (int j=0;j<8;j++) acc[i][j]=0.f;
  }
  const int srow = t>>1, kh = (t&1)*8;
  const int r0 = (t>>4)*8, c0 = (t&15)*8;

  float av[8], avn[8];
  float4 bv0, bv1, bvn0, bvn1;
  LOAD_A(0, avn); LOAD_B(W, H, 0, 0);
  int cur = 0;
  #pragma unroll 1
  for (int k0=0; k0<384; k0+=16){
    #pragma unroll
    for (int j=0;j<8;j++) av[j] = avn[j];
    bv0 = bvn0; bv1 = bvn1;
    COMMIT_AB(cur);
    __syncthreads();
    if (k0+16 < 384){ LOAD_A(k0+16, avn); LOAD_B(W, H, k0+16, 0); }
    FMA16(cur, acc);
    cur ^= 1;
  }

  float bi[8];
  { float4 x0 = *(const float4*)&bias[c0]; float4 x1 = *(const float4*)&bias[c0+4];
    bi[0]=x0.x;bi[1]=x0.y;bi[2]=x0.z;bi[3]=x0.w;bi[4]=x1.x;bi[5]=x1.y;bi[6]=x1.z;bi[7]=x1.w; }
  if (MODE==0){
    float wd[8];
    float4 y0=*(const float4*)&W[(size_t)384*H + c0];
    float4 y1=*(const float4*)&W[(size_t)384*H + c0+4];
    wd[0]=y0.x;wd[1]=y0.y;wd[2]=y0.z;wd[3]=y0.w;wd[4]=y1.x;wd[5]=y1.y;wd[6]=y1.z;wd[7]=y1.w;
    #pragma unroll
    for (int r=0;r<8;r++){
      float dv = dist[eidl[r0+r]];
      #pragma unroll
      for (int c=0;c<8;c++) acc[r][c] += bi[c] + dv*wd[c];
    }
    __syncthreads();   // GEMM LDS reads done before Cst overlay
    // stage silu -> seg-reduce to agg
    #pragma unroll
    for (int r=0;r<8;r++){
      float sv[8];
      #pragma unroll
      for (int c=0;c<8;c++) sv[c] = siluf(acc[r][c]);
      st_bf8(&Cst[(size_t)(r0+r)*128 + c0], sv);
    }
    __syncthreads();
    seg_walk(Cst, didx, agg, t);
    __syncthreads();
    // stage dsilu -> seg-reduce to Tf
    #pragma unroll
    for (int r=0;r<8;r++){
      float sv[8];
      #pragma unroll
      for (int c=0;c<8;c++) sv[c] = dsilu(acc[r][c]);
      st_bf8(&Cst[(size_t)(r0+r)*128 + c0], sv);
    }
    __syncthreads();
    seg_walk(Cst, didx, Tf, t);
  } else {
    #pragma unroll
    for (int r=0;r<8;r++){
      u16* ep = eb + (size_t)eidl[r0+r]*H + c0;
      float ev[8]; ld_bf8(ep, ev);
      #pragma unroll
      for (int c=0;c<8;c++) ev[c] += siluf(acc[r][c]+bi[c]);
      st_bf8(ep, ev);
    }
  }
}

// ---------- fused edge backward (src-sorted via perm_s) ----------
// MODE 0: msg bwd: A = dagg[dst]*dsilu(pre); jc {2:de, 0:dh-src seg-reduced}; pdist. (dst side via T.)
// MODE 1: eu  bwd: A = de*dsilu(pre);        jc {2:de, 1:dh-dst atomics, 0:dh-src seg-reduced}.
template<int MODE>
__global__ __launch_bounds__(256) void ebwd(
    const u16* __restrict__ hb, const u16* __restrict__ eb,
    const float* __restrict__ dist, const int* __restrict__ ei,
    const int* __restrict__ perm,
    const float* __restrict__ W, const float* __restrict__ bias,
    const float* __restrict__ mulf, const float* __restrict__ WT,
    float* __restrict__ dh, u16* __restrict__ de, float* __restrict__ ddist)
{
  const int ldB = (MODE==0) ? 388 : 384;
  __shared__ __align__(16) u16 Au16[128*128];      // 32KB: phase1 AstF overlay, then A, then C0 stage
  __shared__ __align__(16) float Bs[2][16][128];   // 16KB
  __shared__ int eidl[128], sidx[128], didx[128];
  float (*AstF)[16][128] = (float(*)[16][128])Au16;
  const int t = threadIdx.x;
  const int e0 = blockIdx.x * 128;
  if (t < 128){
    int eid = perm[e0+t];
    eidl[t] = eid; sidx[t] = ei[eid]; didx[t] = ei[NE+eid];
  }
  __syncthreads();
  const int srow = t>>1, kh = (t&1)*8;
  const int r0 = (t>>4)*8, c0 = (t&15)*8;
  const int tq = t>>4, t15 = t&15;

  // ---- phase 1: pre ----
  float pre[8][8];
  #pragma unroll
  for (int i=0;i<8;i++){
    #pragma unroll
    for (int j=0;j<8;j++) pre[i][j]=0.f;
  }
  {
    float av[8], avn[8];
    float4 bv0, bv1, bvn0, bvn1;
    LOAD_A(0, avn); LOAD_B(W, H, 0, 0);
    int cur = 0;
    #pragma unroll 1
    for (int k0=0; k0<384; k0+=16){
      #pragma unroll
      for (int j=0;j<8;j++) av[j] = avn[j];
      bv0 = bvn0; bv1 = bvn1;
      COMMIT_AB(cur);
      __syncthreads();
      if (k0+16 < 384){ LOAD_A(k0+16, avn); LOAD_B(W, H, k0+16, 0); }
      FMA16(cur, pre);
      cur ^= 1;
    }
  }
  {
    float bi[8];
    float4 x0 = *(const float4*)&bias[c0]; float4 x1 = *(const float4*)&bias[c0+4];
    bi[0]=x0.x;bi[1]=x0.y;bi[2]=x0.z;bi[3]=x0.w;bi[4]=x1.x;bi[5]=x1.y;bi[6]=x1.z;bi[7]=x1.w;
    float wd[8] = {0,0,0,0,0,0,0,0};
    if (MODE==0){
      float4 y0=*(const float4*)&W[(size_t)384*H + c0];
      float4 y1=*(const float4*)&W[(size_t)384*H + c0+4];
      wd[0]=y0.x;wd[1]=y0.y;wd[2]=y0.z;wd[3]=y0.w;wd[4]=y1.x;wd[5]=y1.y;wd[6]=y1.z;wd[7]=y1.w;
    }
    #pragma unroll
    for (int r=0;r<8;r++){
      float dv = (MODE==0) ? dist[eidl[r0+r]] : 0.f;
      #pragma unroll
      for (int c=0;c<8;c++) pre[r][c] += bi[c] + dv*wd[c];
    }
  }

  // ---- phase 2: A = mul * dsilu(pre) ----
  #pragma unroll
  for (int r=0;r<8;r++){
    float mv[8];
    if (MODE==0){
      const float* mp = mulf + (size_t)didx[r0+r]*H + c0;
      float4 m0 = *(const float4*)mp, m1 = *(const float4*)(mp+4);
      mv[0]=m0.x;mv[1]=m0.y;mv[2]=m0.z;mv[3]=m0.w;mv[4]=m1.x;mv[5]=m1.y;mv[6]=m1.z;mv[7]=m1.w;
    } else {
      ld_bf8(de + (size_t)eidl[r0+r]*H + c0, mv);
    }
    #pragma unroll
    for (int c=0;c<8;c++) pre[r][c] = mv[c]*dsilu(pre[r][c]);
  }

  // ---- pdist (MODE 0): exact f32, shfl reduce across 16 col-groups ----
  if (MODE==0){
    float wdist[8];
    #pragma unroll
    for (int j=0;j<8;j++) wdist[j] = WT[(size_t)(c0+j)*388 + 384];
    #pragma unroll
    for (int r=0;r<8;r++){
      float pd = 0.f;
      #pragma unroll
      for (int j=0;j<8;j++) pd = fmaf(pre[r][j], wdist[j], pd);
      pd += __shfl_xor(pd, 1);
      pd += __shfl_xor(pd, 2);
      pd += __shfl_xor(pd, 4);
      pd += __shfl_xor(pd, 8);
      if (t15 == 0) ddist[eidl[r0+r]] += pd;
    }
  }

  // ---- stage A^T (bf16, swizzled) ----
  __syncthreads();
  #pragma unroll
  for (int j=0;j<8;j++){
    uint4 q;
    q.x = pack2(pre[0][j], pre[1][j]);
    q.y = pack2(pre[2][j], pre[3][j]);
    q.z = pack2(pre[4][j], pre[5][j]);
    q.w = pack2(pre[6][j], pre[7][j]);
    *(uint4*)&Au16[(size_t)(c0+j)*128 + ((tq ^ t15) & 15)*8] = q;
  }
  __syncthreads();

  // ---- phase 3: GEMM chunks over jc list ----
  const int njc = (MODE==0) ? 2 : 3;
  const int jcl[3] = {2, (MODE==0)?0:1, 0};
  float4 bvn0, bvn1;
  LOAD_B(WT, ldB, 0, jcl[0]*128);
  int cur = 0;
  float acc[8][8];
  #pragma unroll
  for (int i=0;i<8;i++){
    #pragma unroll
    for (int j=0;j<8;j++) acc[i][j]=0.f;
  }
  const int nsteps = njc*8;
  #pragma unroll 1
  for (int s=0; s<nsteps; s++){
    const int k0 = (s&7)*16;
    *(float4*)&Bs[cur][t>>5][(t&31)*4]     = bvn0;
    *(float4*)&Bs[cur][(t>>5)+8][(t&31)*4] = bvn1;
    __syncthreads();
    if (s+1 < nsteps){ int s2 = s+1; LOAD_B(WT, ldB, (s2&7)*16, jcl[s2>>3]*128); }
    #pragma unroll
    for (int kk=0;kk<16;kk++){
      int ka = k0 + kk;
      float avv[8];
      ld_bf8(&Au16[(size_t)ka*128 + ((tq ^ ((ka>>3)&15)) & 15)*8], avv);
      float4 b0 = *(const float4*)&Bs[cur][kk][c0];
      float4 b1 = *(const float4*)&Bs[cur][kk][c0+4];
      float bvv[8] = {b0.x,b0.y,b0.z,b0.w,b1.x,b1.y,b1.z,b1.w};
      #pragma unroll
      for (int r=0;r<8;r++){
        #pragma unroll
        for (int c=0;c<8;c++) acc[r][c] = fmaf(avv[r], bvv[c], acc[r][c]);
      }
    }
    cur ^= 1;
    if ((s&7) == 7){
      const int jc = jcl[s>>3];
      if (jc == 2){
        #pragma unroll
        for (int r=0;r<8;r++){
          u16* ep = de + (size_t)eidl[r0+r]*H + c0;
          float ev[8]; ld_bf8(ep, ev);
          #pragma unroll
          for (int c=0;c<8;c++) ev[c] += acc[r][c];
          st_bf8(ep, ev);
        }
      } else if (jc == 1){
        #pragma unroll
        for (int r=0;r<8;r++){
          int dn = didx[r0+r];
          #pragma unroll
          for (int c=0;c<8;c++) atomicAdd(&dh[(size_t)dn*H + c0 + c], acc[r][c]);
        }
      } else {
        // jc==0 (last step): stage C0 into Au16 (plain), seg-reduce by src into dh
        __syncthreads();   // all Au16 (A) reads complete
        #pragma unroll
        for (int r=0;r<8;r++) st_bf8(&Au16[(size_t)(r0+r)*128 + c0], acc[r]);
        __syncthreads();
        seg_walk(Au16, sidx, dh, t);
      }
      #pragma unroll
      for (int i=0;i<8;i++){
        #pragma unroll
        for (int j=0;j<8;j++) acc[i][j]=0.f;
      }
    }
  }
}

// ---------- T convert: T_l = bf16(Tf), Tf := 0 ----------
__global__ __launch_bounds__(256) void tcvt_k(u16* __restrict__ T, float* __restrict__ Tf){
  size_t i = (size_t)blockIdx.x*256 + threadIdx.x;
  T[i] = f2bf(Tf[i]);
  Tf[i] = 0.f;
}

// ---------- dst-side msg grad via T: dh += (dagg .* T) @ WT1 ----------
__global__ __launch_bounds__(128) void dstmsg_k(const float* __restrict__ dagg,
                                                const u16* __restrict__ T,
                                                const float* __restrict__ WmT,
                                                float* __restrict__ dh){
  __shared__ float s[128];
  int n = blockIdx.x, c = threadIdx.x;
  s[c] = dagg[(size_t)n*H + c] * bf2f(T[(size_t)n*H + c]);
  __syncthreads();
  float acc = 0.f;
  #pragma unroll 4
  for (int k=0;k<128;k++) acc = fmaf(s[k], WmT[(size_t)k*388 + 128 + c], acc);
  dh[(size_t)n*H + c] += acc;
}

// ---------- node update forward ----------
__global__ __launch_bounds__(128) void upd_fwd(
    const u16* __restrict__ hin, const float* __restrict__ agg,
    const float* __restrict__ Wu, const float* __restrict__ bu,
    const float* __restrict__ g, const float* __restrict__ bln,
    u16* __restrict__ upre, float* __restrict__ lnst, u16* __restrict__ hout)
{
  __shared__ float ha[256];
  __shared__ float sb[4];
  int n = blockIdx.x, c = threadIdx.x;
  float hv = bf2f(hin[(size_t)n*H + c]);
  ha[c] = hv;
  ha[128+c] = agg[(size_t)n*H + c];
  __syncthreads();
  float s = bu[c];
  #pragma unroll 4
  for (int k=0;k<256;k++) s = fmaf(ha[k], Wu[(size_t)k*H + c], s);
  upre[(size_t)n*H + c] = f2bf(s);
  float2 ms = blockSum2_128(s, s*s, sb);
  float mu = ms.x*(1.f/128.f);
  float var = ms.y*(1.f/128.f) - mu*mu;
  float rstd = rsqrtf(var + 1e-5f);
  if (c == 0){ lnst[(size_t)n*2+0] = mu; lnst[(size_t)n*2+1] = rstd; }
  float uh = (s - mu)*rstd;
  float un = uh*g[c] + bln[c];
  hout[(size_t)n*H + c] = f2bf(hv + siluf(un));
}

// ---------- final MLP fused fwd+bwd -> dh ----------
__global__ __launch_bounds__(128) void final_fused(
    const u16* __restrict__ h, const float* __restrict__ Wo, const float* __restrict__ bo,
    const float* __restrict__ Wh1, const float* __restrict__ bh1v,
    const float* __restrict__ Wh2, float* __restrict__ dh)
{
  __shared__ float sh[128], sf[64], sdz[32], sdf[64];
  int n = blockIdx.x, c = threadIdx.x;
  sh[c] = bf2f(h[(size_t)n*H + c]);
  __syncthreads();
  if (c < 64){
    float s = bo[c];
    #pragma unroll 4
    for (int k=0;k<128;k++) s = fmaf(sh[k], Wo[(size_t)k*64 + c], s);
    sf[c] = s;
  }
  __syncthreads();
  if (c < 32){
    float s = bh1v[c];
    #pragma unroll 4
    for (int j=0;j<64;j++) s = fmaf(sf[j], Wh1[(size_t)j*32 + c], s);
    sdz[c] = Wh2[c]*dsilu(s);
  }
  __syncthreads();
  if (c < 64){
    float s = 0.f;
    #pragma unroll 4
    for (int k=0;k<32;k++) s = fmaf(sdz[k], Wh1[(size_t)c*32 + k], s);
    sdf[c] = s;
  }
  __syncthreads();
  {
    float s = 0.f;
    #pragma unroll 4
    for (int j=0;j<64;j++) s = fmaf(sdf[j], Wo[(size_t)c*64 + j], s);
    dh[(size_t)n*H + c] = s;
  }
}

// ---------- node update backward ----------
__global__ __launch_bounds__(128) void upd_bwd(
    float* __restrict__ dh, float* __restrict__ dagg,
    const u16* __restrict__ upre, const float* __restrict__ lnst,
    const float* __restrict__ WuT,
    const float* __restrict__ g, const float* __restrict__ bln)
{
  __shared__ float sh[128];
  __shared__ float sb[4];
  int n = blockIdx.x, c = threadIdx.x;
  float up   = bf2f(upre[(size_t)n*H + c]);
  float mu   = lnst[(size_t)n*2+0];
  float rstd = lnst[(size_t)n*2+1];
  float uh = (up - mu)*rstd;
  float un = uh*g[c] + bln[c];
  float dhv = dh[(size_t)n*H + c];
  float dun = dhv * dsilu(un);
  float duh = dun * g[c];
  float2 m12 = blockSum2_128(duh, duh*uh, sb);
  float m1 = m12.x*(1.f/128.f), m2 = m12.y*(1.f/128.f);
  float dup = (duh - m1 - uh*m2)*rstd;
  sh[c] = dup;
  __syncthreads();
  float s0 = 0.f, s1 = 0.f;
  #pragma unroll 4
  for (int k=0;k<128;k++){
    float d = sh[k];
    s0 = fmaf(d, WuT[(size_t)k*256 + c], s0);
    s1 = fmaf(d, WuT[(size_t)k*256 + 128 + c], s1);
  }
  dh[(size_t)n*H + c] = dhv + s0;
  dagg[(size_t)n*H + c] = s1;
}

// ---------- dist -> dpos ----------
__global__ void rel_bwd(const float* __restrict__ y, const float* __restrict__ dist,
                        const float* __restrict__ ddist, const int* __restrict__ ei,
                        float* __restrict__ dpos){
  int e = blockIdx.x*256 + threadIdx.x;
  if (e >= NE) return;
  int s = ei[e], d = ei[NE+e];
  float gsc = ddist[e]/dist[e];
  #pragma unroll
  for (int i=0;i<3;i++){
    float dr = gsc*(y[(size_t)d*6+i] - y[(size_t)s*6+i]);
    atomicAdd(&dpos[(size_t)d*3+i],  dr);
    atomicAdd(&dpos[(size_t)s*3+i], -dr);
  }
}

// ---------- output (f32) ----------
__global__ void out_k(const float* __restrict__ y, const float* __restrict__ dpos,
                      float* __restrict__ out){
  int n = blockIdx.x*256 + threadIdx.x;
  if (n >= NN) return;
  #pragma unroll
  for (int i=0;i<3;i++) out[(size_t)n*6+i]   =  y[(size_t)n*6+3+i];
  #pragma unroll
  for (int i=0;i<3;i++) out[(size_t)n*6+3+i] = -dpos[(size_t)n*3+i];
}

// ---------- host ----------
extern "C" void kernel_launch(void* const* d_in, const int* in_sizes, int n_in,
                              void* d_out, int out_size, void* d_ws, size_t ws_size,
                              hipStream_t stream)
{
  const float* y   = (const float*)d_in[0];
  const float* x   = (const float*)d_in[1];
  const float* ea  = (const float*)d_in[2];
  const int*   ei  = (const int*)d_in[3];
  const float* Wn  = (const float*)d_in[4];
  const float* bn  = (const float*)d_in[5];
  const float* We5 = (const float*)d_in[6];
  const float* be5 = (const float*)d_in[7];
  const float* Wm  = (const float*)d_in[8];
  const float* bm  = (const float*)d_in[9];
  const float* Wu  = (const float*)d_in[10];
  const float* bu  = (const float*)d_in[11];
  const float* lg  = (const float*)d_in[12];
  const float* lb  = (const float*)d_in[13];
  const float* We  = (const float*)d_in[14];
  const float* beu = (const float*)d_in[15];
  const float* Wo  = (const float*)d_in[16];
  const float* bo  = (const float*)d_in[17];
  const float* Wh1 = (const float*)d_in[18];
  const float* bh1v= (const float*)d_in[19];
  const float* Wh2 = (const float*)d_in[20];
  float* out = (float*)d_out;

  if (ws_size < WS_NEED){
    diag_k<<<1, 1, 0, stream>>>(out, 4000.f + (float)(ws_size >> 20));
    return;
  }

  char* ws = (char*)d_ws;
  u16*   h5    = (u16*)  (ws + OFF_H5);
  u16*   upre  = (u16*)  (ws + OFF_UPRE);
  float* lnst  = (float*)(ws + OFF_LNST);
  u16*   T     = (u16*)  (ws + OFF_T);
  u16*   eb    = (u16*)  (ws + OFF_E);
  u16*   de    = (u16*)  (ws + OFF_DE);
  float* aggd  = (float*)(ws + OFF_AGG);
  float* dh    = (float*)(ws + OFF_DH);     // Tf during forward
  float* dist  = (float*)(ws + OFF_DIST);
  float* ddist = (float*)(ws + OFF_DDIST);
  float* dpos  = (float*)(ws + OFF_DPOS);
  float* WmT   = (float*)(ws + OFF_WMT);
  float* WeT   = (float*)(ws + OFF_WET);
  float* WuT   = (float*)(ws + OFF_WUT);
  int*   perm_d= (int*)  (ws + OFF_PD);
  int*   perm_s= (int*)  (ws + OFF_PS);
  int*   curd  = (int*)  (ws + OFF_CURD);
  int*   curs  = (int*)  (ws + OFF_CURS);

  hipMemsetAsync(ddist, 0, (size_t)NE*4, stream);
  hipMemsetAsync(dpos,  0, (size_t)NN*3*4, stream);
  hipMemsetAsync(de,    0, NEH*2, stream);
  hipMemsetAsync(dh,    0, NNH*4, stream);
  hipMemsetAsync(curd,  0, (size_t)NN*4, stream);
  hipMemsetAsync(curs,  0, (size_t)NN*4, stream);

  transpose_w<<<512, 256, 0, stream>>>(Wm, We, Wu, WmT, WeT, WuT);
  node_emb<<<NN, 128, 0, stream>>>(x, Wn, bn, h5);
  edge_emb<<<NE/2, 256, 0, stream>>>(ea, We5, be5, eb);
  rel_dist<<<NE/256, 256, 0, stream>>>(y, ei, dist);

  // ---- sort (dst- and src-ordered permutations) ----
  hist_k<<<NE/256, 256, 0, stream>>>(ei, curs, curd);
  scan_k<<<1, 256, 0, stream>>>(curd, curs);
  fill_k<<<NE/256, 256, 0, stream>>>(ei, curs, curd, perm_s, perm_d);

  // ---- forward ----
  for (int l=0; l<NL; l++){
    hipMemsetAsync(aggd, 0, NNH*4, stream);
    efwd<0><<<NE/128, 256, 0, stream>>>(h5 + l*NNH, eb, dist, ei, perm_d,
        Wm + (size_t)l*385*H, bm + (size_t)l*H, aggd, dh);
    tcvt_k<<<(int)(NNH/256), 256, 0, stream>>>(T + l*NNH, dh);
    upd_fwd<<<NN, 128, 0, stream>>>(h5 + l*NNH, aggd,
        Wu + (size_t)l*256*H, bu + (size_t)l*H,
        lg + (size_t)l*H, lb + (size_t)l*H,
        upre + l*NNH, lnst + (size_t)l*NN*2, h5 + (l+1)*NNH);
    if (l < NL-1){
      efwd<1><<<NE/128, 256, 0, stream>>>(h5 + (l+1)*NNH, eb, nullptr, ei, nullptr,
          We + (size_t)l*384*H, beu + (size_t)l*H, nullptr, nullptr);
    }
  }

  final_fused<<<NN, 128, 0, stream>>>(h5 + (size_t)NL*NNH, Wo, bo, Wh1, bh1v, Wh2, dh);

  // ---- backward ----
  for (int l=NL-1; l>=0; l--){
    if (l < NL-1){
      edge_emb<<<NE/2, 256, 0, stream>>>(ea, We5, be5, eb);
      for (int k=0; k<l; k++){
        efwd<1><<<NE/128, 256, 0, stream>>>(h5 + (k+1)*NNH, eb, nullptr, ei, nullptr,
            We + (size_t)k*384*H, beu + (size_t)k*H, nullptr, nullptr);
      }
      ebwd<1><<<NE/128, 256, 0, stream>>>(h5 + (l+1)*NNH, eb, nullptr, ei, perm_s,
          We + (size_t)l*384*H, beu + (size_t)l*H, nullptr,
          WeT + (size_t)l*128*384, dh, de, nullptr);
    }
    upd_bwd<<<NN, 128, 0, stream>>>(dh, aggd, upre + l*NNH, lnst + (size_t)l*NN*2,
        WuT + (size_t)l*128*256, lg + (size_t)l*H, lb + (size_t)l*H);
    dstmsg_k<<<NN, 128, 0, stream>>>(aggd, T + l*NNH, WmT + (size_t)l*128*388, dh);
    ebwd<0><<<NE/128, 256, 0, stream>>>(h5 + l*NNH, eb, dist, ei, perm_s,
        Wm + (size_t)l*385*H, bm + (size_t)l*H, aggd,
        WmT + (size_t)l*128*388, dh, de, ddist);
  }

  rel_bwd<<<NE/256, 256, 0, stream>>>(y, dist, ddist, ei, dpos);
  out_k<<<(NN+255)/256, 256, 0, stream>>>(y, dpos, out);
}

// Round 12
// 4555.770 us; speedup vs baseline: 5.9212x; 3.3907x over previous
//
#include <hip/hip_runtime.h>
#include <hip/hip_bf16.h>

#define NN 20000
#define NE 320000
#define H  128
#define NL 4

typedef unsigned int uint;
typedef unsigned short u16;
typedef short s8v __attribute__((ext_vector_type(8)));
typedef float fx4 __attribute__((ext_vector_type(4)));

static constexpr size_t NNH = (size_t)NN*H;
static constexpr size_t NEH = (size_t)NE*H;

// ---------- workspace layout (bytes), total 260,718,208 (proven ws >= 261,545,344) ----------
static constexpr size_t OFF_H5    = 0;                                // h5   [5][NN][H] bf16
static constexpr size_t OFF_UPRE  = OFF_H5    + 5*NNH*2;              // upre [4][NN][H] bf16
static constexpr size_t OFF_LNST  = OFF_UPRE  + 4*NNH*2;              // lnst [4][NN][2] f32
static constexpr size_t OFF_T     = OFF_LNST  + (size_t)4*NN*2*4;     // T [4][NN][H] bf16
static constexpr size_t OFF_E     = OFF_T     + 4*NNH*2;              // e [NE][H] bf16
static constexpr size_t OFF_DE    = OFF_E     + NEH*2;                // de [NE][H] bf16
static constexpr size_t OFF_AGG   = OFF_DE    + NEH*2;                // agg/dagg [NN][H] f32
static constexpr size_t OFF_DH    = OFF_AGG   + NNH*4;                // dh [NN][H] f32 (Tf in fwd)
static constexpr size_t OFF_DIST  = OFF_DH    + NNH*4;                // dist [NE] f32
static constexpr size_t OFF_DDIST = OFF_DIST  + (size_t)NE*4;         // ddist [NE] f32
static constexpr size_t OFF_DPOS  = OFF_DDIST + (size_t)NE*4;         // dpos [NN][3] f32
static constexpr size_t OFF_WMT   = OFF_DPOS  + (size_t)NN*3*4;       // WmT [NL][128][388] f32
static constexpr size_t OFF_WET   = OFF_WMT   + (size_t)NL*128*388*4; // WeT [NL][128][384] f32
static constexpr size_t OFF_WUT   = OFF_WET   + (size_t)NL*128*384*4; // WuT [NL][128][256] f32
static constexpr size_t OFF_PD    = OFF_WUT   + (size_t)NL*128*256*4; // perm_d [NE] int
static constexpr size_t OFF_PS    = OFF_PD    + (size_t)NE*4;         // perm_s [NE] int
static constexpr size_t OFF_CURD  = OFF_PS    + (size_t)NE*4;         // curd [NN] int
static constexpr size_t OFF_CURS  = OFF_CURD  + (size_t)NN*4;         // curs [NN] int
// packed bf16 weight fragments (per layer stride 49152 u16)
static constexpr size_t OFF_WMP   = OFF_CURS  + (size_t)NN*4;         // [NL][12][8][64][8]
static constexpr size_t OFF_WEP   = OFF_WMP   + (size_t)NL*49152*2;
static constexpr size_t OFF_WMTP  = OFF_WEP   + (size_t)NL*49152*2;   // [NL][4][24][64][8]
static constexpr size_t OFF_WETP  = OFF_WMTP  + (size_t)NL*49152*2;
static constexpr size_t WS_NEED   = OFF_WETP  + (size_t)NL*49152*2;

// ---------- helpers ----------
__device__ __forceinline__ float sigm(float x){ return 1.f/(1.f+__expf(-x)); }
__device__ __forceinline__ float siluf(float x){ return x*sigm(x); }
__device__ __forceinline__ float dsilu(float x){ float s=sigm(x); return s*(1.f + x*(1.f-s)); }
__device__ __forceinline__ u16 f2bf(float x){
  uint u = __float_as_uint(x);
  uint r = (u + 0x7fffu + ((u>>16)&1u)) >> 16;
  return (u16)r;
}
__device__ __forceinline__ float bf2f(u16 v){ return __uint_as_float(((uint)v)<<16); }
__device__ __forceinline__ uint pack2(float a, float b){ return (uint)f2bf(a) | ((uint)f2bf(b)<<16); }
__device__ __forceinline__ void ld_bf8(const u16* p, float* v){
  uint4 q = *(const uint4*)p;
  v[0]=__uint_as_float(q.x<<16); v[1]=__uint_as_float(q.x&0xffff0000u);
  v[2]=__uint_as_float(q.y<<16); v[3]=__uint_as_float(q.y&0xffff0000u);
  v[4]=__uint_as_float(q.z<<16); v[5]=__uint_as_float(q.z&0xffff0000u);
  v[6]=__uint_as_float(q.w<<16); v[7]=__uint_as_float(q.w&0xffff0000u);
}
__device__ __forceinline__ void st_bf8(u16* p, const float* v){
  uint4 o;
  o.x = pack2(v[0],v[1]); o.y = pack2(v[2],v[3]);
  o.z = pack2(v[4],v[5]); o.w = pack2(v[6],v[7]);
  *(uint4*)p = o;
}

__device__ __forceinline__ float2 blockSum2_128(float a, float b, float* sb){
  #pragma unroll
  for (int off=32; off>0; off>>=1){ a += __shfl_down(a, off); b += __shfl_down(b, off); }
  int t = threadIdx.x;
  if ((t&63)==0){ sb[(t>>6)*2+0]=a; sb[(t>>6)*2+1]=b; }
  __syncthreads();
  float2 r; r.x = sb[0]+sb[2]; r.y = sb[1]+sb[3];
  __syncthreads();
  return r;
}

// segment-reduce staged rows (Cst [128 rows][136 stride] bf16) by LDS keys.
__device__ __forceinline__ void seg_walk136(const u16* Cst, const int* keys, float* buf, int t){
  int c = t & 127, half = t >> 7;
  int i0 = half*64, i1 = i0 + 64;
  float acc = 0.f; int k = keys[i0];
  #pragma unroll 4
  for (int i=i0; i<i1; i++){
    int ki = keys[i];
    if (ki != k){ atomicAdd(&buf[(size_t)k*H + c], acc); acc = 0.f; k = ki; }
    acc += bf2f(Cst[(size_t)i*136 + c]);
  }
  atomicAdd(&buf[(size_t)k*H + c], acc);
}

__global__ void diag_k(float* out, float v){ out[0] = v; }

// ---------- sort construction ----------
__global__ void hist_k(const int* __restrict__ ei, int* __restrict__ curs, int* __restrict__ curd){
  int e = blockIdx.x*256 + threadIdx.x;
  if (e >= NE) return;
  atomicAdd(&curs[ei[e]], 1);
  atomicAdd(&curd[ei[NE+e]], 1);
}

__global__ void scan_k(int* __restrict__ curd, int* __restrict__ curs){
  __shared__ int sm[256];
  for (int a=0; a<2; a++){
    int* p = a ? curs : curd;
    int run = 0;
    for (int base=0; base<NN; base+=256){
      int idx = base + threadIdx.x;
      sm[threadIdx.x] = (idx < NN) ? p[idx] : 0;
      __syncthreads();
      if (threadIdx.x == 0){
        int acc = run;
        for (int i=0;i<256;i++){ int v = sm[i]; sm[i] = acc; acc += v; }
        run = acc;
      }
      __syncthreads();
      if (idx < NN) p[idx] = sm[threadIdx.x];
      __syncthreads();
    }
  }
}

__global__ void fill_k(const int* __restrict__ ei, int* __restrict__ curs, int* __restrict__ curd,
                       int* __restrict__ perm_s, int* __restrict__ perm_d){
  int e = blockIdx.x*256 + threadIdx.x;
  if (e >= NE) return;
  perm_s[atomicAdd(&curs[ei[e]], 1)] = e;
  perm_d[atomicAdd(&curd[ei[NE+e]], 1)] = e;
}

// ---------- weight transposes ----------
__global__ void transpose_w(const float* __restrict__ Wm, const float* __restrict__ We,
                            const float* __restrict__ Wu,
                            float* __restrict__ WmT, float* __restrict__ WeT,
                            float* __restrict__ WuT){
  int idx = blockIdx.x*blockDim.x + threadIdx.x;
  int stride = gridDim.x*blockDim.x;
  for (int i=idx; i<NL*128*388; i+=stride){
    int l = i/(128*388), r = i - l*128*388, k = r/388, j = r - k*388;
    WmT[i] = (j<385) ? Wm[((size_t)l*385 + j)*H + k] : 0.f;
  }
  for (int i=idx; i<NL*128*384; i+=stride){
    int l = i/(128*384), r = i - l*128*384, k = r/384, j = r - k*384;
    WeT[i] = We[((size_t)l*384 + j)*H + k];
  }
  for (int i=idx; i<NL*128*256; i+=stride){
    int l = i/(128*256), r = i - l*128*256, k = r/256, j = r - k*256;
    WuT[i] = Wu[((size_t)l*256 + j)*H + k];
  }
}

// ---------- pack weights into MFMA B-fragment order ----------
// dst[l][ks*NC+ct][lane][j] = bf16(src[l][k=ks*32+(lane>>4)*8+j][c=ct*16+(lane&15)])
__global__ __launch_bounds__(64) void pack_k(const float* __restrict__ src, u16* __restrict__ dst,
                      int KS, int NC, int ld, size_t sStride, size_t dStride){
  int b = blockIdx.x;
  int l = b/(KS*NC); int r = b - l*KS*NC; int ks = r/NC; int ct = r - ks*NC;
  int lane = threadIdx.x;
  #pragma unroll
  for (int j=0;j<8;j++){
    int k = ks*32 + (lane>>4)*8 + j;
    int c = ct*16 + (lane&15);
    dst[l*dStride + ((size_t)(ks*NC+ct)*64 + lane)*8 + j] =
        f2bf(src[l*sStride + (size_t)k*ld + c]);
  }
}

// ---------- small kernels ----------
__global__ __launch_bounds__(128) void node_emb(const float* __restrict__ x,
                                                const float* __restrict__ Wn,
                                                const float* __restrict__ bn,
                                                u16* __restrict__ h){
  __shared__ float xs[16];
  int n = blockIdx.x, c = threadIdx.x;
  if (c < 16) xs[c] = x[(size_t)n*16 + c];
  __syncthreads();
  float s = bn[c];
  #pragma unroll
  for (int k=0;k<16;k++) s = fmaf(xs[k], Wn[k*H + c], s);
  h[(size_t)n*H + c] = f2bf(s);
}

__global__ __launch_bounds__(256) void edge_emb(const float* __restrict__ ea,
                                                const float* __restrict__ We5,
                                                const float* __restrict__ be,
                                                u16* __restrict__ ebuf){
  int e = blockIdx.x*2 + (threadIdx.x>>7);
  int c = threadIdx.x & 127;
  const float* row = ea + (size_t)e*8;
  float v;
  if (c < 3) v = row[c];
  else {
    int j = c-3;
    float s = be[j];
    #pragma unroll
    for (int k=0;k<5;k++) s = fmaf(row[3+k], We5[k*125 + j], s);
    v = s;
  }
  ebuf[(size_t)e*H + c] = f2bf(v);
}

__global__ void rel_dist(const float* __restrict__ y, const int* __restrict__ ei,
                         float* __restrict__ dist){
  int e = blockIdx.x*256 + threadIdx.x;
  if (e >= NE) return;
  int s = ei[e], d = ei[NE+e];
  float rx = y[(size_t)d*6+0] - y[(size_t)s*6+0];
  float ry = y[(size_t)d*6+1] - y[(size_t)s*6+1];
  float rz = y[(size_t)d*6+2] - y[(size_t)s*6+2];
  dist[e] = sqrtf(rx*rx + ry*ry + rz*rz + 1e-8f);
}

// ---------- MFMA phase-1: pre = [h_s|h_d|e] @ W (K=384) ----------
// acc[rt][ct] fragments; rows = wid*32 + rt*16 + (C-layout), cols = ct*16 + li
#define PHASE1_MFMA(ACC)                                                          \
  _Pragma("unroll 1")                                                             \
  for (int s=0; s<12; s++){                                                       \
    s8v av0, av1;                                                                 \
    {                                                                             \
      int k = s*32 + l4*8;                                                        \
      int row0 = wid*32 + li, row1 = row0 + 16;                                   \
      const u16 *p0, *p1;                                                         \
      if (k < 128){ p0 = hb + (size_t)sidx[row0]*H + k;                           \
                    p1 = hb + (size_t)sidx[row1]*H + k; }                         \
      else if (k < 256){ p0 = hb + (size_t)didx[row0]*H + (k-128);                \
                         p1 = hb + (size_t)didx[row1]*H + (k-128); }              \
      else { p0 = eb + (size_t)eidl[row0]*H + (k-256);                            \
             p1 = eb + (size_t)eidl[row1]*H + (k-256); }                          \
      av0 = *(const s8v*)p0; av1 = *(const s8v*)p1;                               \
    }                                                                             \
    _Pragma("unroll")                                                             \
    for (int ct=0; ct<8; ct++){                                                   \
      s8v bv = *(const s8v*)&WP[((size_t)(s*8+ct)*64 + lane)*8];                  \
      ACC[0][ct] = __builtin_amdgcn_mfma_f32_16x16x32_bf16(av0, bv, ACC[0][ct], 0,0,0); \
      ACC[1][ct] = __builtin_amdgcn_mfma_f32_16x16x32_bf16(av1, bv, ACC[1][ct], 0,0,0); \
    }                                                                             \
  }

// ---------- edge GEMM forward (MFMA) ----------
// MODE 0: msg, dst-sorted; seg-reduce silu->agg, dsilu->Tf.  MODE 1: eu, e += silu.
template<int MODE>
__global__ __launch_bounds__(256) void efwd(
    const u16* __restrict__ hb, u16* __restrict__ eb,
    const float* __restrict__ dist, const int* __restrict__ ei,
    const int* __restrict__ perm,
    const float* __restrict__ Wf, const float* __restrict__ bias,
    const u16* __restrict__ WP,
    float* __restrict__ agg, float* __restrict__ Tf)
{
  __shared__ __align__(16) u16 Als[128*136];
  __shared__ int eidl[128], sidx[128], didx[128];
  const int t = threadIdx.x;
  const int e0 = blockIdx.x * 128;
  if (t < 128){
    int eid = perm ? perm[e0+t] : (e0+t);
    eidl[t] = eid; sidx[t] = ei[eid]; didx[t] = ei[NE+eid];
  }
  __syncthreads();
  const int lane = t&63, wid = t>>6, l4 = lane>>4, li = lane&15;

  fx4 acc[2][8];
  #pragma unroll
  for (int i=0;i<2;i++){
    #pragma unroll
    for (int j=0;j<8;j++) acc[i][j] = (fx4){0.f,0.f,0.f,0.f};
  }
  PHASE1_MFMA(acc)

  // bias (+ dist*wd for MODE 0)
  float dv[2][4];
  if (MODE==0){
    #pragma unroll
    for (int rt=0;rt<2;rt++){
      #pragma unroll
      for (int reg=0;reg<4;reg++) dv[rt][reg] = dist[eidl[wid*32+rt*16+l4*4+reg]];
    }
  }
  #pragma unroll
  for (int ct=0; ct<8; ct++){
    int c = ct*16 + li;
    float bi = bias[c];
    float wd = (MODE==0) ? Wf[(size_t)384*H + c] : 0.f;
    #pragma unroll
    for (int rt=0;rt<2;rt++){
      #pragma unroll
      for (int reg=0;reg<4;reg++)
        acc[rt][ct][reg] += bi + ((MODE==0) ? dv[rt][reg]*wd : 0.f);
    }
  }

  if (MODE==0){
    // silu -> agg
    __syncthreads();
    #pragma unroll
    for (int rt=0;rt<2;rt++){
      #pragma unroll
      for (int reg=0;reg<4;reg++){
        int brow = wid*32+rt*16+l4*4+reg;
        #pragma unroll
        for (int ct=0;ct<8;ct++)
          Als[(size_t)brow*136 + ct*16+li] = f2bf(siluf(acc[rt][ct][reg]));
      }
    }
    __syncthreads();
    seg_walk136(Als, didx, agg, t);
    __syncthreads();
    // dsilu -> Tf
    #pragma unroll
    for (int rt=0;rt<2;rt++){
      #pragma unroll
      for (int reg=0;reg<4;reg++){
        int brow = wid*32+rt*16+l4*4+reg;
        #pragma unroll
        for (int ct=0;ct<8;ct++)
          Als[(size_t)brow*136 + ct*16+li] = f2bf(dsilu(acc[rt][ct][reg]));
      }
    }
    __syncthreads();
    seg_walk136(Als, didx, Tf, t);
  } else {
    // e += silu
    __syncthreads();
    #pragma unroll
    for (int rt=0;rt<2;rt++){
      #pragma unroll
      for (int reg=0;reg<4;reg++){
        int brow = wid*32+rt*16+l4*4+reg;
        #pragma unroll
        for (int ct=0;ct<8;ct++)
          Als[(size_t)brow*136 + ct*16+li] = f2bf(siluf(acc[rt][ct][reg]));
      }
    }
    __syncthreads();
    int row = t>>1, coff = (t&1)*64;
    u16* dst = eb + (size_t)eidl[row]*H + coff;
    #pragma unroll
    for (int i=0;i<8;i++){
      float a[8], b[8];
      ld_bf8(&Als[(size_t)row*136 + coff + i*8], a);
      ld_bf8(&dst[i*8], b);
      #pragma unroll
      for (int j=0;j<8;j++) b[j] += a[j];
      st_bf8(&dst[i*8], b);
    }
  }
}

// ---------- fused edge backward (MFMA, src-sorted) ----------
// MODE 0: msg bwd: jc {2:de, 0:dh-src seg}; pdist. MODE 1: eu bwd: jc {2:de, 1:dh-dst atomics, 0:dh-src seg}.
template<int MODE>
__global__ __launch_bounds__(256) void ebwd(
    const u16* __restrict__ hb, const u16* __restrict__ eb,
    const float* __restrict__ dist, const int* __restrict__ ei,
    const int* __restrict__ perm,
    const float* __restrict__ Wf, const float* __restrict__ bias,
    const float* __restrict__ mulf, const float* __restrict__ WTf,
    const u16* __restrict__ WP, const u16* __restrict__ WTP,
    float* __restrict__ dh, u16* __restrict__ de, float* __restrict__ ddist)
{
  __shared__ __align__(16) u16 Als[128*136];
  __shared__ int eidl[128], sidx[128], didx[128];
  const int t = threadIdx.x;
  const int e0 = blockIdx.x * 128;
  if (t < 128){
    int eid = perm[e0+t];
    eidl[t] = eid; sidx[t] = ei[eid]; didx[t] = ei[NE+eid];
  }
  __syncthreads();
  const int lane = t&63, wid = t>>6, l4 = lane>>4, li = lane&15;

  // ---- phase 1 ----
  fx4 acc[2][8];
  #pragma unroll
  for (int i=0;i<2;i++){
    #pragma unroll
    for (int j=0;j<8;j++) acc[i][j] = (fx4){0.f,0.f,0.f,0.f};
  }
  PHASE1_MFMA(acc)

  float dv[2][4];
  if (MODE==0){
    #pragma unroll
    for (int rt=0;rt<2;rt++){
      #pragma unroll
      for (int reg=0;reg<4;reg++) dv[rt][reg] = dist[eidl[wid*32+rt*16+l4*4+reg]];
    }
  }
  #pragma unroll
  for (int ct=0; ct<8; ct++){
    int c = ct*16 + li;
    float bi = bias[c];
    float wd = (MODE==0) ? Wf[(size_t)384*H + c] : 0.f;
    #pragma unroll
    for (int rt=0;rt<2;rt++){
      #pragma unroll
      for (int reg=0;reg<4;reg++)
        acc[rt][ct][reg] += bi + ((MODE==0) ? dv[rt][reg]*wd : 0.f);
    }
  }

  // ---- phase 2: A = mul * dsilu(pre) ----
  if (MODE==1){
    // stage de rows to LDS for vectorized access
    {
      int row = t>>1, coff = (t&1)*64;
      const u16* src = de + (size_t)eidl[row]*H + coff;
      #pragma unroll
      for (int i=0;i<8;i++)
        *(uint4*)&Als[(size_t)row*136 + coff + i*8] = *(const uint4*)&src[i*8];
    }
    __syncthreads();
  }
  #pragma unroll
  for (int rt=0;rt<2;rt++){
    #pragma unroll
    for (int reg=0;reg<4;reg++){
      int brow = wid*32+rt*16+l4*4+reg;
      #pragma unroll
      for (int ct=0;ct<8;ct++){
        int c = ct*16+li;
        float m;
        if (MODE==0) m = mulf[(size_t)didx[brow]*H + c];
        else         m = bf2f(Als[(size_t)brow*136 + c]);
        acc[rt][ct][reg] = m * dsilu(acc[rt][ct][reg]);
      }
    }
  }

  // ---- pdist (MODE 0): exact f32, shfl reduce over li ----
  if (MODE==0){
    float wdT[8];
    #pragma unroll
    for (int ct=0;ct<8;ct++) wdT[ct] = WTf[(size_t)(ct*16+li)*388 + 384];
    #pragma unroll
    for (int rt=0;rt<2;rt++){
      #pragma unroll
      for (int reg=0;reg<4;reg++){
        float pd = 0.f;
        #pragma unroll
        for (int ct=0;ct<8;ct++) pd = fmaf(acc[rt][ct][reg], wdT[ct], pd);
        pd += __shfl_xor(pd, 1);
        pd += __shfl_xor(pd, 2);
        pd += __shfl_xor(pd, 4);
        pd += __shfl_xor(pd, 8);
        if (li == 0) ddist[eidl[wid*32+rt*16+l4*4+reg]] += pd;
      }
    }
  }

  // ---- stage A bf16 to LDS ----
  __syncthreads();
  #pragma unroll
  for (int rt=0;rt<2;rt++){
    #pragma unroll
    for (int reg=0;reg<4;reg++){
      int brow = wid*32+rt*16+l4*4+reg;
      #pragma unroll
      for (int ct=0;ct<8;ct++)
        Als[(size_t)brow*136 + ct*16+li] = f2bf(acc[rt][ct][reg]);
    }
  }
  __syncthreads();

  // hoist A fragments (rows = wid*32 + rt*16 + li; k = ks*32 + l4*8)
  s8v afr[2][4];
  #pragma unroll
  for (int rt=0;rt<2;rt++){
    int row = wid*32 + rt*16 + li;
    #pragma unroll
    for (int ks=0;ks<4;ks++)
      afr[rt][ks] = *(const s8v*)&Als[(size_t)row*136 + ks*32 + l4*8];
  }

  // ---- phase 3 ----
  const int njc = (MODE==0) ? 2 : 3;
  const int jcl[3] = {2, (MODE==0)?0:1, 0};
  #pragma unroll 1
  for (int ji=0; ji<njc; ji++){
    const int jc = jcl[ji];
    #pragma unroll
    for (int i=0;i<2;i++){
      #pragma unroll
      for (int j=0;j<8;j++) acc[i][j] = (fx4){0.f,0.f,0.f,0.f};
    }
    #pragma unroll
    for (int ks=0;ks<4;ks++){
      #pragma unroll
      for (int ct=0;ct<8;ct++){
        s8v bv = *(const s8v*)&WTP[((size_t)(ks*24 + jc*8 + ct)*64 + lane)*8];
        acc[0][ct] = __builtin_amdgcn_mfma_f32_16x16x32_bf16(afr[0][ks], bv, acc[0][ct], 0,0,0);
        acc[1][ct] = __builtin_amdgcn_mfma_f32_16x16x32_bf16(afr[1][ks], bv, acc[1][ct], 0,0,0);
      }
    }
    if (jc == 1){
      #pragma unroll
      for (int rt=0;rt<2;rt++){
        #pragma unroll
        for (int reg=0;reg<4;reg++){
          int dn = didx[wid*32+rt*16+l4*4+reg];
          #pragma unroll
          for (int ct=0;ct<8;ct++)
            atomicAdd(&dh[(size_t)dn*H + ct*16+li], acc[rt][ct][reg]);
        }
      }
    } else {
      __syncthreads();   // prior Als readers done
      #pragma unroll
      for (int rt=0;rt<2;rt++){
        #pragma unroll
        for (int reg=0;reg<4;reg++){
          int brow = wid*32+rt*16+l4*4+reg;
          #pragma unroll
          for (int ct=0;ct<8;ct++)
            Als[(size_t)brow*136 + ct*16+li] = f2bf(acc[rt][ct][reg]);
        }
      }
      __syncthreads();
      if (jc == 2){
        int row = t>>1, coff = (t&1)*64;
        u16* dst = de + (size_t)eidl[row]*H + coff;
        #pragma unroll
        for (int i=0;i<8;i++){
          float a[8], b[8];
          ld_bf8(&Als[(size_t)row*136 + coff + i*8], a);
          ld_bf8(&dst[i*8], b);
          #pragma unroll
          for (int j=0;j<8;j++) b[j] += a[j];
          st_bf8(&dst[i*8], b);
        }
      } else {
        seg_walk136(Als, sidx, dh, t);
      }
    }
  }
}

// ---------- T convert ----------
__global__ __launch_bounds__(256) void tcvt_k(u16* __restrict__ T, float* __restrict__ Tf){
  size_t i = (size_t)blockIdx.x*256 + threadIdx.x;
  T[i] = f2bf(Tf[i]);
  Tf[i] = 0.f;
}

// ---------- dst-side msg grad via T ----------
__global__ __launch_bounds__(128) void dstmsg_k(const float* __restrict__ dagg,
                                                const u16* __restrict__ T,
                                                const float* __restrict__ WmT,
                                                float* __restrict__ dh){
  __shared__ float s[128];
  int n = blockIdx.x, c = threadIdx.x;
  s[c] = dagg[(size_t)n*H + c] * bf2f(T[(size_t)n*H + c]);
  __syncthreads();
  float acc = 0.f;
  #pragma unroll 4
  for (int k=0;k<128;k++) acc = fmaf(s[k], WmT[(size_t)k*388 + 128 + c], acc);
  dh[(size_t)n*H + c] += acc;
}

// ---------- node update forward ----------
__global__ __launch_bounds__(128) void upd_fwd(
    const u16* __restrict__ hin, const float* __restrict__ agg,
    const float* __restrict__ Wu, const float* __restrict__ bu,
    const float* __restrict__ g, const float* __restrict__ bln,
    u16* __restrict__ upre, float* __restrict__ lnst, u16* __restrict__ hout)
{
  __shared__ float ha[256];
  __shared__ float sb[4];
  int n = blockIdx.x, c = threadIdx.x;
  float hv = bf2f(hin[(size_t)n*H + c]);
  ha[c] = hv;
  ha[128+c] = agg[(size_t)n*H + c];
  __syncthreads();
  float s = bu[c];
  #pragma unroll 4
  for (int k=0;k<256;k++) s = fmaf(ha[k], Wu[(size_t)k*H + c], s);
  upre[(size_t)n*H + c] = f2bf(s);
  float2 ms = blockSum2_128(s, s*s, sb);
  float mu = ms.x*(1.f/128.f);
  float var = ms.y*(1.f/128.f) - mu*mu;
  float rstd = rsqrtf(var + 1e-5f);
  if (c == 0){ lnst[(size_t)n*2+0] = mu; lnst[(size_t)n*2+1] = rstd; }
  float uh = (s - mu)*rstd;
  float un = uh*g[c] + bln[c];
  hout[(size_t)n*H + c] = f2bf(hv + siluf(un));
}

// ---------- final MLP fused fwd+bwd ----------
__global__ __launch_bounds__(128) void final_fused(
    const u16* __restrict__ h, const float* __restrict__ Wo, const float* __restrict__ bo,
    const float* __restrict__ Wh1, const float* __restrict__ bh1v,
    const float* __restrict__ Wh2, float* __restrict__ dh)
{
  __shared__ float sh[128], sf[64], sdz[32], sdf[64];
  int n = blockIdx.x, c = threadIdx.x;
  sh[c] = bf2f(h[(size_t)n*H + c]);
  __syncthreads();
  if (c < 64){
    float s = bo[c];
    #pragma unroll 4
    for (int k=0;k<128;k++) s = fmaf(sh[k], Wo[(size_t)k*64 + c], s);
    sf[c] = s;
  }
  __syncthreads();
  if (c < 32){
    float s = bh1v[c];
    #pragma unroll 4
    for (int j=0;j<64;j++) s = fmaf(sf[j], Wh1[(size_t)j*32 + c], s);
    sdz[c] = Wh2[c]*dsilu(s);
  }
  __syncthreads();
  if (c < 64){
    float s = 0.f;
    #pragma unroll 4
    for (int k=0;k<32;k++) s = fmaf(sdz[k], Wh1[(size_t)c*32 + k], s);
    sdf[c] = s;
  }
  __syncthreads();
  {
    float s = 0.f;
    #pragma unroll 4
    for (int j=0;j<64;j++) s = fmaf(sdf[j], Wo[(size_t)c*64 + j], s);
    dh[(size_t)n*H + c] = s;
  }
}

// ---------- node update backward ----------
__global__ __launch_bounds__(128) void upd_bwd(
    float* __restrict__ dh, float* __restrict__ dagg,
    const u16* __restrict__ upre, const float* __restrict__ lnst,
    const float* __restrict__ WuT,
    const float* __restrict__ g, const float* __restrict__ bln)
{
  __shared__ float sh[128];
  __shared__ float sb[4];
  int n = blockIdx.x, c = threadIdx.x;
  float up   = bf2f(upre[(size_t)n*H + c]);
  float mu   = lnst[(size_t)n*2+0];
  float rstd = lnst[(size_t)n*2+1];
  float uh = (up - mu)*rstd;
  float un = uh*g[c] + bln[c];
  float dhv = dh[(size_t)n*H + c];
  float dun = dhv * dsilu(un);
  float duh = dun * g[c];
  float2 m12 = blockSum2_128(duh, duh*uh, sb);
  float m1 = m12.x*(1.f/128.f), m2 = m12.y*(1.f/128.f);
  float dup = (duh - m1 - uh*m2)*rstd;
  sh[c] = dup;
  __syncthreads();
  float s0 = 0.f, s1 = 0.f;
  #pragma unroll 4
  for (int k=0;k<128;k++){
    float d = sh[k];
    s0 = fmaf(d, WuT[(size_t)k*256 + c], s0);
    s1 = fmaf(d, WuT[(size_t)k*256 + 128 + c], s1);
  }
  dh[(size_t)n*H + c] = dhv + s0;
  dagg[(size_t)n*H + c] = s1;
}

// ---------- dist -> dpos ----------
__global__ void rel_bwd(const float* __restrict__ y, const float* __restrict__ dist,
                        const float* __restrict__ ddist, const int* __restrict__ ei,
                        float* __restrict__ dpos){
  int e = blockIdx.x*256 + threadIdx.x;
  if (e >= NE) return;
  int s = ei[e], d = ei[NE+e];
  float gsc = ddist[e]/dist[e];
  #pragma unroll
  for (int i=0;i<3;i++){
    float dr = gsc*(y[(size_t)d*6+i] - y[(size_t)s*6+i]);
    atomicAdd(&dpos[(size_t)d*3+i],  dr);
    atomicAdd(&dpos[(size_t)s*3+i], -dr);
  }
}

// ---------- output (f32) ----------
__global__ void out_k(const float* __restrict__ y, const float* __restrict__ dpos,
                      float* __restrict__ out){
  int n = blockIdx.x*256 + threadIdx.x;
  if (n >= NN) return;
  #pragma unroll
  for (int i=0;i<3;i++) out[(size_t)n*6+i]   =  y[(size_t)n*6+3+i];
  #pragma unroll
  for (int i=0;i<3;i++) out[(size_t)n*6+3+i] = -dpos[(size_t)n*3+i];
}

// ---------- host ----------
extern "C" void kernel_launch(void* const* d_in, const int* in_sizes, int n_in,
                              void* d_out, int out_size, void* d_ws, size_t ws_size,
                              hipStream_t stream)
{
  const float* y   = (const float*)d_in[0];
  const float* x   = (const float*)d_in[1];
  const float* ea  = (const float*)d_in[2];
  const int*   ei  = (const int*)d_in[3];
  const float* Wn  = (const float*)d_in[4];
  const float* bn  = (const float*)d_in[5];
  const float* We5 = (const float*)d_in[6];
  const float* be5 = (const float*)d_in[7];
  const float* Wm  = (const float*)d_in[8];
  const float* bm  = (const float*)d_in[9];
  const float* Wu  = (const float*)d_in[10];
  const float* bu  = (const float*)d_in[11];
  const float* lg  = (const float*)d_in[12];
  const float* lb  = (const float*)d_in[13];
  const float* We  = (const float*)d_in[14];
  const float* beu = (const float*)d_in[15];
  const float* Wo  = (const float*)d_in[16];
  const float* bo  = (const float*)d_in[17];
  const float* Wh1 = (const float*)d_in[18];
  const float* bh1v= (const float*)d_in[19];
  const float* Wh2 = (const float*)d_in[20];
  float* out = (float*)d_out;

  if (ws_size < WS_NEED){
    diag_k<<<1, 1, 0, stream>>>(out, 4000.f + (float)(ws_size >> 20));
    return;
  }

  char* ws = (char*)d_ws;
  u16*   h5    = (u16*)  (ws + OFF_H5);
  u16*   upre  = (u16*)  (ws + OFF_UPRE);
  float* lnst  = (float*)(ws + OFF_LNST);
  u16*   T     = (u16*)  (ws + OFF_T);
  u16*   eb    = (u16*)  (ws + OFF_E);
  u16*   de    = (u16*)  (ws + OFF_DE);
  float* aggd  = (float*)(ws + OFF_AGG);
  float* dh    = (float*)(ws + OFF_DH);     // Tf during forward
  float* dist  = (float*)(ws + OFF_DIST);
  float* ddist = (float*)(ws + OFF_DDIST);
  float* dpos  = (float*)(ws + OFF_DPOS);
  float* WmT   = (float*)(ws + OFF_WMT);
  float* WeT   = (float*)(ws + OFF_WET);
  float* WuT   = (float*)(ws + OFF_WUT);
  int*   perm_d= (int*)  (ws + OFF_PD);
  int*   perm_s= (int*)  (ws + OFF_PS);
  int*   curd  = (int*)  (ws + OFF_CURD);
  int*   curs  = (int*)  (ws + OFF_CURS);
  u16*   WmP   = (u16*)  (ws + OFF_WMP);
  u16*   WeP   = (u16*)  (ws + OFF_WEP);
  u16*   WmTP  = (u16*)  (ws + OFF_WMTP);
  u16*   WeTP  = (u16*)  (ws + OFF_WETP);

  hipMemsetAsync(ddist, 0, (size_t)NE*4, stream);
  hipMemsetAsync(dpos,  0, (size_t)NN*3*4, stream);
  hipMemsetAsync(de,    0, NEH*2, stream);
  hipMemsetAsync(dh,    0, NNH*4, stream);
  hipMemsetAsync(curd,  0, (size_t)NN*4, stream);
  hipMemsetAsync(curs,  0, (size_t)NN*4, stream);

  transpose_w<<<512, 256, 0, stream>>>(Wm, We, Wu, WmT, WeT, WuT);
  // pack MFMA B-fragments (fwd K=384 from Wm/We; bwd K=128 from WmT/WeT)
  pack_k<<<NL*12*8, 64, 0, stream>>>(Wm,  WmP,  12, 8,  128, (size_t)385*128, 49152);
  pack_k<<<NL*12*8, 64, 0, stream>>>(We,  WeP,  12, 8,  128, (size_t)384*128, 49152);
  pack_k<<<NL*4*24, 64, 0, stream>>>(WmT, WmTP, 4,  24, 388, (size_t)128*388, 49152);
  pack_k<<<NL*4*24, 64, 0, stream>>>(WeT, WeTP, 4,  24, 384, (size_t)128*384, 49152);

  node_emb<<<NN, 128, 0, stream>>>(x, Wn, bn, h5);
  edge_emb<<<NE/2, 256, 0, stream>>>(ea, We5, be5, eb);
  rel_dist<<<NE/256, 256, 0, stream>>>(y, ei, dist);

  hist_k<<<NE/256, 256, 0, stream>>>(ei, curs, curd);
  scan_k<<<1, 256, 0, stream>>>(curd, curs);
  fill_k<<<NE/256, 256, 0, stream>>>(ei, curs, curd, perm_s, perm_d);

  // ---- forward ----
  for (int l=0; l<NL; l++){
    hipMemsetAsync(aggd, 0, NNH*4, stream);
    efwd<0><<<NE/128, 256, 0, stream>>>(h5 + l*NNH, eb, dist, ei, perm_d,
        Wm + (size_t)l*385*H, bm + (size_t)l*H, WmP + (size_t)l*49152, aggd, dh);
    tcvt_k<<<(int)(NNH/256), 256, 0, stream>>>(T + l*NNH, dh);
    upd_fwd<<<NN, 128, 0, stream>>>(h5 + l*NNH, aggd,
        Wu + (size_t)l*256*H, bu + (size_t)l*H,
        lg + (size_t)l*H, lb + (size_t)l*H,
        upre + l*NNH, lnst + (size_t)l*NN*2, h5 + (l+1)*NNH);
    if (l < NL-1){
      efwd<1><<<NE/128, 256, 0, stream>>>(h5 + (l+1)*NNH, eb, nullptr, ei, nullptr,
          We + (size_t)l*384*H, beu + (size_t)l*H, WeP + (size_t)l*49152, nullptr, nullptr);
    }
  }

  final_fused<<<NN, 128, 0, stream>>>(h5 + (size_t)NL*NNH, Wo, bo, Wh1, bh1v, Wh2, dh);

  // ---- backward ----
  for (int l=NL-1; l>=0; l--){
    if (l < NL-1){
      edge_emb<<<NE/2, 256, 0, stream>>>(ea, We5, be5, eb);
      for (int k=0; k<l; k++){
        efwd<1><<<NE/128, 256, 0, stream>>>(h5 + (k+1)*NNH, eb, nullptr, ei, nullptr,
            We + (size_t)k*384*H, beu + (size_t)k*H, WeP + (size_t)k*49152, nullptr, nullptr);
      }
      ebwd<1><<<NE/128, 256, 0, stream>>>(h5 + (l+1)*NNH, eb, nullptr, ei, perm_s,
          We + (size_t)l*384*H, beu + (size_t)l*H, nullptr, nullptr,
          WeP + (size_t)l*49152, WeTP + (size_t)l*49152, dh, de, nullptr);
    }
    upd_bwd<<<NN, 128, 0, stream>>>(dh, aggd, upre + l*NNH, lnst + (size_t)l*NN*2,
        WuT + (size_t)l*128*256, lg + (size_t)l*H, lb + (size_t)l*H);
    dstmsg_k<<<NN, 128, 0, stream>>>(aggd, T + l*NNH, WmT + (size_t)l*128*388, dh);
    ebwd<0><<<NE/128, 256, 0, stream>>>(h5 + l*NNH, eb, dist, ei, perm_s,
        Wm + (size_t)l*385*H, bm + (size_t)l*H, aggd, WmT + (size_t)l*128*388,
        WmP + (size_t)l*49152, WmTP + (size_t)l*49152, dh, de, ddist);
  }

  rel_bwd<<<NE/256, 256, 0, stream>>>(y, dist, ddist, ei, dpos);
  out_k<<<(NN+255)/256, 256, 0, stream>>>(y, dpos, out);
}

// Round 13
// 3780.144 us; speedup vs baseline: 7.1362x; 1.2052x over previous
//
#include <hip/hip_runtime.h>
#include <hip/hip_bf16.h>

#define NN 20000
#define NE 320000
#define H  128
#define NL 4

typedef unsigned int uint;
typedef unsigned short u16;
typedef short s8v __attribute__((ext_vector_type(8)));
typedef float fx4 __attribute__((ext_vector_type(4)));

static constexpr size_t NNH = (size_t)NN*H;
static constexpr size_t NEH = (size_t)NE*H;

// ---------- workspace layout (bytes), total 260,718,208 ----------
static constexpr size_t OFF_H5    = 0;                                // h5   [5][NN][H] bf16
static constexpr size_t OFF_UPRE  = OFF_H5    + 5*NNH*2;              // upre [4][NN][H] bf16
static constexpr size_t OFF_LNST  = OFF_UPRE  + 4*NNH*2;              // lnst [4][NN][2] f32
static constexpr size_t OFF_T     = OFF_LNST  + (size_t)4*NN*2*4;     // T [4][NN][H] bf16
static constexpr size_t OFF_E     = OFF_T     + 4*NNH*2;              // e [NE][H] bf16
static constexpr size_t OFF_DE    = OFF_E     + NEH*2;                // de [NE][H] bf16
static constexpr size_t OFF_AGG   = OFF_DE    + NEH*2;                // agg/dagg [NN][H] f32
static constexpr size_t OFF_DH    = OFF_AGG   + NNH*4;                // dh [NN][H] f32 (Tf in fwd)
static constexpr size_t OFF_DIST  = OFF_DH    + NNH*4;                // dist [NE] f32
static constexpr size_t OFF_DDIST = OFF_DIST  + (size_t)NE*4;         // ddist [NE] f32
static constexpr size_t OFF_DPOS  = OFF_DDIST + (size_t)NE*4;         // dpos [NN][3] f32
static constexpr size_t OFF_WMT   = OFF_DPOS  + (size_t)NN*3*4;       // WmT [NL][128][388] f32
static constexpr size_t OFF_WET   = OFF_WMT   + (size_t)NL*128*388*4; // WeT [NL][128][384] f32
static constexpr size_t OFF_WUT   = OFF_WET   + (size_t)NL*128*384*4; // WuT [NL][128][256] f32
static constexpr size_t OFF_PD    = OFF_WUT   + (size_t)NL*128*256*4; // perm_d [NE] int
static constexpr size_t OFF_PS    = OFF_PD    + (size_t)NE*4;         // perm_s [NE] int
static constexpr size_t OFF_CURD  = OFF_PS    + (size_t)NE*4;         // curd [NN] int
static constexpr size_t OFF_CURS  = OFF_CURD  + (size_t)NN*4;         // curs [NN] int
static constexpr size_t OFF_WMP   = OFF_CURS  + (size_t)NN*4;         // [NL][12][8][64][8] bf16
static constexpr size_t OFF_WEP   = OFF_WMP   + (size_t)NL*49152*2;
static constexpr size_t OFF_WMTP  = OFF_WEP   + (size_t)NL*49152*2;   // [NL][4][24][64][8]
static constexpr size_t OFF_WETP  = OFF_WMTP  + (size_t)NL*49152*2;
static constexpr size_t WS_NEED   = OFF_WETP  + (size_t)NL*49152*2;

// ---------- helpers ----------
__device__ __forceinline__ float sigm(float x){ return 1.f/(1.f+__expf(-x)); }
__device__ __forceinline__ float siluf(float x){ return x*sigm(x); }
__device__ __forceinline__ float dsilu(float x){ float s=sigm(x); return s*(1.f + x*(1.f-s)); }
__device__ __forceinline__ u16 f2bf(float x){
  uint u = __float_as_uint(x);
  uint r = (u + 0x7fffu + ((u>>16)&1u)) >> 16;
  return (u16)r;
}
__device__ __forceinline__ float bf2f(u16 v){ return __uint_as_float(((uint)v)<<16); }
__device__ __forceinline__ uint pack2(float a, float b){ return (uint)f2bf(a) | ((uint)f2bf(b)<<16); }
__device__ __forceinline__ void ld_bf8(const u16* p, float* v){
  uint4 q = *(const uint4*)p;
  v[0]=__uint_as_float(q.x<<16); v[1]=__uint_as_float(q.x&0xffff0000u);
  v[2]=__uint_as_float(q.y<<16); v[3]=__uint_as_float(q.y&0xffff0000u);
  v[4]=__uint_as_float(q.z<<16); v[5]=__uint_as_float(q.z&0xffff0000u);
  v[6]=__uint_as_float(q.w<<16); v[7]=__uint_as_float(q.w&0xffff0000u);
}
__device__ __forceinline__ void st_bf8(u16* p, const float* v){
  uint4 o;
  o.x = pack2(v[0],v[1]); o.y = pack2(v[2],v[3]);
  o.z = pack2(v[4],v[5]); o.w = pack2(v[6],v[7]);
  *(uint4*)p = o;
}

__device__ __forceinline__ float2 blockSum2_128(float a, float b, float* sb){
  #pragma unroll
  for (int off=32; off>0; off>>=1){ a += __shfl_down(a, off); b += __shfl_down(b, off); }
  int t = threadIdx.x;
  if ((t&63)==0){ sb[(t>>6)*2+0]=a; sb[(t>>6)*2+1]=b; }
  __syncthreads();
  float2 r; r.x = sb[0]+sb[2]; r.y = sb[1]+sb[3];
  __syncthreads();
  return r;
}

// segment-reduce staged rows (Cst [128 rows][136 stride] bf16) by LDS keys.
__device__ __forceinline__ void seg_walk136(const u16* Cst, const int* keys, float* buf, int t){
  int c = t & 127, half = t >> 7;
  int i0 = half*64, i1 = i0 + 64;
  float acc = 0.f; int k = keys[i0];
  #pragma unroll 4
  for (int i=i0; i<i1; i++){
    int ki = keys[i];
    if (ki != k){ atomicAdd(&buf[(size_t)k*H + c], acc); acc = 0.f; k = ki; }
    acc += bf2f(Cst[(size_t)i*136 + c]);
  }
  atomicAdd(&buf[(size_t)k*H + c], acc);
}

__global__ void diag_k(float* out, float v){ out[0] = v; }

// ---------- sort construction ----------
__global__ void hist_k(const int* __restrict__ ei, int* __restrict__ curs, int* __restrict__ curd){
  int e = blockIdx.x*256 + threadIdx.x;
  if (e >= NE) return;
  atomicAdd(&curs[ei[e]], 1);
  atomicAdd(&curd[ei[NE+e]], 1);
}

// parallel exclusive scan over curd then curs (NN elements each)
__global__ __launch_bounds__(256) void scan_k(int* __restrict__ curd, int* __restrict__ curs){
  __shared__ int ps[256];
  const int t = threadIdx.x;
  const int CH = (NN + 255)/256;   // 79
  for (int a=0; a<2; a++){
    int* p = a ? curs : curd;
    int lo = t*CH, hi = lo+CH < NN ? lo+CH : NN;
    int sum = 0;
    for (int i=lo; i<hi; i++) sum += p[i];
    ps[t] = sum;
    __syncthreads();
    #pragma unroll
    for (int off=1; off<256; off<<=1){
      int v = (t>=off) ? ps[t-off] : 0;
      __syncthreads();
      ps[t] += v;
      __syncthreads();
    }
    int run = (t==0) ? 0 : ps[t-1];
    for (int i=lo; i<hi; i++){ int v = p[i]; p[i] = run; run += v; }
    __syncthreads();
  }
}

__global__ void fill_k(const int* __restrict__ ei, int* __restrict__ curs, int* __restrict__ curd,
                       int* __restrict__ perm_s, int* __restrict__ perm_d){
  int e = blockIdx.x*256 + threadIdx.x;
  if (e >= NE) return;
  perm_s[atomicAdd(&curs[ei[e]], 1)] = e;
  perm_d[atomicAdd(&curd[ei[NE+e]], 1)] = e;
}

// ---------- weight transposes ----------
__global__ void transpose_w(const float* __restrict__ Wm, const float* __restrict__ We,
                            const float* __restrict__ Wu,
                            float* __restrict__ WmT, float* __restrict__ WeT,
                            float* __restrict__ WuT){
  int idx = blockIdx.x*blockDim.x + threadIdx.x;
  int stride = gridDim.x*blockDim.x;
  for (int i=idx; i<NL*128*388; i+=stride){
    int l = i/(128*388), r = i - l*128*388, k = r/388, j = r - k*388;
    WmT[i] = (j<385) ? Wm[((size_t)l*385 + j)*H + k] : 0.f;
  }
  for (int i=idx; i<NL*128*384; i+=stride){
    int l = i/(128*384), r = i - l*128*384, k = r/384, j = r - k*384;
    WeT[i] = We[((size_t)l*384 + j)*H + k];
  }
  for (int i=idx; i<NL*128*256; i+=stride){
    int l = i/(128*256), r = i - l*128*256, k = r/256, j = r - k*256;
    WuT[i] = Wu[((size_t)l*256 + j)*H + k];
  }
}

// ---------- pack weights into MFMA B-fragment order ----------
__global__ __launch_bounds__(64) void pack_k(const float* __restrict__ src, u16* __restrict__ dst,
                      int KS, int NC, int ld, size_t sStride, size_t dStride){
  int b = blockIdx.x;
  int l = b/(KS*NC); int r = b - l*KS*NC; int ks = r/NC; int ct = r - ks*NC;
  int lane = threadIdx.x;
  #pragma unroll
  for (int j=0;j<8;j++){
    int k = ks*32 + (lane>>4)*8 + j;
    int c = ct*16 + (lane&15);
    dst[l*dStride + ((size_t)(ks*NC+ct)*64 + lane)*8 + j] =
        f2bf(src[l*sStride + (size_t)k*ld + c]);
  }
}

// ---------- small kernels ----------
__global__ __launch_bounds__(128) void node_emb(const float* __restrict__ x,
                                                const float* __restrict__ Wn,
                                                const float* __restrict__ bn,
                                                u16* __restrict__ h){
  __shared__ float xs[16];
  int n = blockIdx.x, c = threadIdx.x;
  if (c < 16) xs[c] = x[(size_t)n*16 + c];
  __syncthreads();
  float s = bn[c];
  #pragma unroll
  for (int k=0;k<16;k++) s = fmaf(xs[k], Wn[k*H + c], s);
  h[(size_t)n*H + c] = f2bf(s);
}

__global__ __launch_bounds__(256) void edge_emb(const float* __restrict__ ea,
                                                const float* __restrict__ We5,
                                                const float* __restrict__ be,
                                                u16* __restrict__ ebuf){
  int e = blockIdx.x*2 + (threadIdx.x>>7);
  int c = threadIdx.x & 127;
  const float* row = ea + (size_t)e*8;
  float v;
  if (c < 3) v = row[c];
  else {
    int j = c-3;
    float s = be[j];
    #pragma unroll
    for (int k=0;k<5;k++) s = fmaf(row[3+k], We5[k*125 + j], s);
    v = s;
  }
  ebuf[(size_t)e*H + c] = f2bf(v);
}

__global__ void rel_dist(const float* __restrict__ y, const int* __restrict__ ei,
                         float* __restrict__ dist){
  int e = blockIdx.x*256 + threadIdx.x;
  if (e >= NE) return;
  int s = ei[e], d = ei[NE+e];
  float rx = y[(size_t)d*6+0] - y[(size_t)s*6+0];
  float ry = y[(size_t)d*6+1] - y[(size_t)s*6+1];
  float rz = y[(size_t)d*6+2] - y[(size_t)s*6+2];
  dist[e] = sqrtf(rx*rx + ry*ry + rz*rz + 1e-8f);
}

// ---------- MFMA phase-1: pre = [h_s|h_d|e] @ W (K=384) ----------
#define PHASE1_MFMA(ACC)                                                          \
  _Pragma("unroll 1")                                                             \
  for (int s=0; s<12; s++){                                                       \
    s8v av0, av1;                                                                 \
    {                                                                             \
      int k = s*32 + l4*8;                                                        \
      int row0 = wid*32 + li, row1 = row0 + 16;                                   \
      const u16 *p0, *p1;                                                         \
      if (k < 128){ p0 = hb + (size_t)sidx[row0]*H + k;                           \
                    p1 = hb + (size_t)sidx[row1]*H + k; }                         \
      else if (k < 256){ p0 = hb + (size_t)didx[row0]*H + (k-128);                \
                         p1 = hb + (size_t)didx[row1]*H + (k-128); }              \
      else { p0 = eb + (size_t)eidl[row0]*H + (k-256);                            \
             p1 = eb + (size_t)eidl[row1]*H + (k-256); }                          \
      av0 = *(const s8v*)p0; av1 = *(const s8v*)p1;                               \
    }                                                                             \
    _Pragma("unroll")                                                             \
    for (int ct=0; ct<8; ct++){                                                   \
      s8v bv = *(const s8v*)&WP[((size_t)(s*8+ct)*64 + lane)*8];                  \
      ACC[0][ct] = __builtin_amdgcn_mfma_f32_16x16x32_bf16(av0, bv, ACC[0][ct], 0,0,0); \
      ACC[1][ct] = __builtin_amdgcn_mfma_f32_16x16x32_bf16(av1, bv, ACC[1][ct], 0,0,0); \
    }                                                                             \
  }

// ---------- edge GEMM forward (MFMA) ----------
template<int MODE>
__global__ __launch_bounds__(256) void efwd(
    const u16* __restrict__ hb, u16* __restrict__ eb,
    const float* __restrict__ dist, const int* __restrict__ ei,
    const int* __restrict__ perm,
    const float* __restrict__ Wf, const float* __restrict__ bias,
    const u16* __restrict__ WP,
    float* __restrict__ agg, float* __restrict__ Tf)
{
  __shared__ __align__(16) u16 Als[128*136];
  __shared__ int eidl[128], sidx[128], didx[128];
  const int t = threadIdx.x;
  const int e0 = blockIdx.x * 128;
  if (t < 128){
    int eid = perm ? perm[e0+t] : (e0+t);
    eidl[t] = eid; sidx[t] = ei[eid]; didx[t] = ei[NE+eid];
  }
  __syncthreads();
  const int lane = t&63, wid = t>>6, l4 = lane>>4, li = lane&15;

  fx4 acc[2][8];
  #pragma unroll
  for (int i=0;i<2;i++){
    #pragma unroll
    for (int j=0;j<8;j++) acc[i][j] = (fx4){0.f,0.f,0.f,0.f};
  }
  PHASE1_MFMA(acc)

  float dv[2][4];
  if (MODE==0){
    #pragma unroll
    for (int rt=0;rt<2;rt++){
      #pragma unroll
      for (int reg=0;reg<4;reg++) dv[rt][reg] = dist[eidl[wid*32+rt*16+l4*4+reg]];
    }
  }
  #pragma unroll
  for (int ct=0; ct<8; ct++){
    int c = ct*16 + li;
    float bi = bias[c];
    float wd = (MODE==0) ? Wf[(size_t)384*H + c] : 0.f;
    #pragma unroll
    for (int rt=0;rt<2;rt++){
      #pragma unroll
      for (int reg=0;reg<4;reg++)
        acc[rt][ct][reg] += bi + ((MODE==0) ? dv[rt][reg]*wd : 0.f);
    }
  }

  if (MODE==0){
    __syncthreads();
    #pragma unroll
    for (int rt=0;rt<2;rt++){
      #pragma unroll
      for (int reg=0;reg<4;reg++){
        int brow = wid*32+rt*16+l4*4+reg;
        #pragma unroll
        for (int ct=0;ct<8;ct++)
          Als[(size_t)brow*136 + ct*16+li] = f2bf(siluf(acc[rt][ct][reg]));
      }
    }
    __syncthreads();
    seg_walk136(Als, didx, agg, t);
    __syncthreads();
    #pragma unroll
    for (int rt=0;rt<2;rt++){
      #pragma unroll
      for (int reg=0;reg<4;reg++){
        int brow = wid*32+rt*16+l4*4+reg;
        #pragma unroll
        for (int ct=0;ct<8;ct++)
          Als[(size_t)brow*136 + ct*16+li] = f2bf(dsilu(acc[rt][ct][reg]));
      }
    }
    __syncthreads();
    seg_walk136(Als, didx, Tf, t);
  } else {
    __syncthreads();
    #pragma unroll
    for (int rt=0;rt<2;rt++){
      #pragma unroll
      for (int reg=0;reg<4;reg++){
        int brow = wid*32+rt*16+l4*4+reg;
        #pragma unroll
        for (int ct=0;ct<8;ct++)
          Als[(size_t)brow*136 + ct*16+li] = f2bf(siluf(acc[rt][ct][reg]));
      }
    }
    __syncthreads();
    int row = t>>1, coff = (t&1)*64;
    u16* dst = eb + (size_t)eidl[row]*H + coff;
    #pragma unroll
    for (int i=0;i<8;i++){
      float a[8], b[8];
      ld_bf8(&Als[(size_t)row*136 + coff + i*8], a);
      ld_bf8(&dst[i*8], b);
      #pragma unroll
      for (int j=0;j<8;j++) b[j] += a[j];
      st_bf8(&dst[i*8], b);
    }
  }
}

// ---------- fused edge backward (MFMA, src-sorted) ----------
template<int MODE>
__global__ __launch_bounds__(256) void ebwd(
    const u16* __restrict__ hb, const u16* __restrict__ eb,
    const float* __restrict__ dist, const int* __restrict__ ei,
    const int* __restrict__ perm,
    const float* __restrict__ Wf, const float* __restrict__ bias,
    const float* __restrict__ mulf, const float* __restrict__ WTf,
    const u16* __restrict__ WP, const u16* __restrict__ WTP,
    float* __restrict__ dh, u16* __restrict__ de, float* __restrict__ ddist)
{
  __shared__ __align__(16) u16 Als[128*136];
  __shared__ int eidl[128], sidx[128], didx[128];
  const int t = threadIdx.x;
  const int e0 = blockIdx.x * 128;
  if (t < 128){
    int eid = perm[e0+t];
    eidl[t] = eid; sidx[t] = ei[eid]; didx[t] = ei[NE+eid];
  }
  __syncthreads();
  const int lane = t&63, wid = t>>6, l4 = lane>>4, li = lane&15;

  fx4 acc[2][8];
  #pragma unroll
  for (int i=0;i<2;i++){
    #pragma unroll
    for (int j=0;j<8;j++) acc[i][j] = (fx4){0.f,0.f,0.f,0.f};
  }
  PHASE1_MFMA(acc)

  float dv[2][4];
  if (MODE==0){
    #pragma unroll
    for (int rt=0;rt<2;rt++){
      #pragma unroll
      for (int reg=0;reg<4;reg++) dv[rt][reg] = dist[eidl[wid*32+rt*16+l4*4+reg]];
    }
  }
  #pragma unroll
  for (int ct=0; ct<8; ct++){
    int c = ct*16 + li;
    float bi = bias[c];
    float wd = (MODE==0) ? Wf[(size_t)384*H + c] : 0.f;
    #pragma unroll
    for (int rt=0;rt<2;rt++){
      #pragma unroll
      for (int reg=0;reg<4;reg++)
        acc[rt][ct][reg] += bi + ((MODE==0) ? dv[rt][reg]*wd : 0.f);
    }
  }

  if (MODE==1){
    {
      int row = t>>1, coff = (t&1)*64;
      const u16* src = de + (size_t)eidl[row]*H + coff;
      #pragma unroll
      for (int i=0;i<8;i++)
        *(uint4*)&Als[(size_t)row*136 + coff + i*8] = *(const uint4*)&src[i*8];
    }
    __syncthreads();
  }
  #pragma unroll
  for (int rt=0;rt<2;rt++){
    #pragma unroll
    for (int reg=0;reg<4;reg++){
      int brow = wid*32+rt*16+l4*4+reg;
      #pragma unroll
      for (int ct=0;ct<8;ct++){
        int c = ct*16+li;
        float m;
        if (MODE==0) m = mulf[(size_t)didx[brow]*H + c];
        else         m = bf2f(Als[(size_t)brow*136 + c]);
        acc[rt][ct][reg] = m * dsilu(acc[rt][ct][reg]);
      }
    }
  }

  if (MODE==0){
    float wdT[8];
    #pragma unroll
    for (int ct=0;ct<8;ct++) wdT[ct] = WTf[(size_t)(ct*16+li)*388 + 384];
    #pragma unroll
    for (int rt=0;rt<2;rt++){
      #pragma unroll
      for (int reg=0;reg<4;reg++){
        float pd = 0.f;
        #pragma unroll
        for (int ct=0;ct<8;ct++) pd = fmaf(acc[rt][ct][reg], wdT[ct], pd);
        pd += __shfl_xor(pd, 1);
        pd += __shfl_xor(pd, 2);
        pd += __shfl_xor(pd, 4);
        pd += __shfl_xor(pd, 8);
        if (li == 0) ddist[eidl[wid*32+rt*16+l4*4+reg]] += pd;
      }
    }
  }

  __syncthreads();
  #pragma unroll
  for (int rt=0;rt<2;rt++){
    #pragma unroll
    for (int reg=0;reg<4;reg++){
      int brow = wid*32+rt*16+l4*4+reg;
      #pragma unroll
      for (int ct=0;ct<8;ct++)
        Als[(size_t)brow*136 + ct*16+li] = f2bf(acc[rt][ct][reg]);
    }
  }
  __syncthreads();

  s8v afr[2][4];
  #pragma unroll
  for (int rt=0;rt<2;rt++){
    int row = wid*32 + rt*16 + li;
    #pragma unroll
    for (int ks=0;ks<4;ks++)
      afr[rt][ks] = *(const s8v*)&Als[(size_t)row*136 + ks*32 + l4*8];
  }

  const int njc = (MODE==0) ? 2 : 3;
  const int jcl[3] = {2, (MODE==0)?0:1, 0};
  #pragma unroll 1
  for (int ji=0; ji<njc; ji++){
    const int jc = jcl[ji];
    #pragma unroll
    for (int i=0;i<2;i++){
      #pragma unroll
      for (int j=0;j<8;j++) acc[i][j] = (fx4){0.f,0.f,0.f,0.f};
    }
    #pragma unroll
    for (int ks=0;ks<4;ks++){
      #pragma unroll
      for (int ct=0;ct<8;ct++){
        s8v bv = *(const s8v*)&WTP[((size_t)(ks*24 + jc*8 + ct)*64 + lane)*8];
        acc[0][ct] = __builtin_amdgcn_mfma_f32_16x16x32_bf16(afr[0][ks], bv, acc[0][ct], 0,0,0);
        acc[1][ct] = __builtin_amdgcn_mfma_f32_16x16x32_bf16(afr[1][ks], bv, acc[1][ct], 0,0,0);
      }
    }
    if (jc == 1){
      #pragma unroll
      for (int rt=0;rt<2;rt++){
        #pragma unroll
        for (int reg=0;reg<4;reg++){
          int dn = didx[wid*32+rt*16+l4*4+reg];
          #pragma unroll
          for (int ct=0;ct<8;ct++)
            atomicAdd(&dh[(size_t)dn*H + ct*16+li], acc[rt][ct][reg]);
        }
      }
    } else {
      __syncthreads();
      #pragma unroll
      for (int rt=0;rt<2;rt++){
        #pragma unroll
        for (int reg=0;reg<4;reg++){
          int brow = wid*32+rt*16+l4*4+reg;
          #pragma unroll
          for (int ct=0;ct<8;ct++)
            Als[(size_t)brow*136 + ct*16+li] = f2bf(acc[rt][ct][reg]);
        }
      }
      __syncthreads();
      if (jc == 2){
        int row = t>>1, coff = (t&1)*64;
        u16* dst = de + (size_t)eidl[row]*H + coff;
        #pragma unroll
        for (int i=0;i<8;i++){
          float a[8], b[8];
          ld_bf8(&Als[(size_t)row*136 + coff + i*8], a);
          ld_bf8(&dst[i*8], b);
          #pragma unroll
          for (int j=0;j<8;j++) b[j] += a[j];
          st_bf8(&dst[i*8], b);
        }
      } else {
        seg_walk136(Als, sidx, dh, t);
      }
    }
  }
}

// ---------- node update forward (8 nodes/block, fused T convert) ----------
__global__ __launch_bounds__(128) void upd_fwd(
    const u16* __restrict__ hin, const float* __restrict__ agg,
    const float* __restrict__ Wu, const float* __restrict__ bu,
    const float* __restrict__ g, const float* __restrict__ bln,
    u16* __restrict__ upre, float* __restrict__ lnst, u16* __restrict__ hout,
    u16* __restrict__ T, float* __restrict__ Tf)
{
  __shared__ float ha[8][256];
  __shared__ float sb[4];
  const int n0 = blockIdx.x*8, c = threadIdx.x;
  #pragma unroll
  for (int n=0;n<8;n++){
    ha[n][c]     = bf2f(hin[(size_t)(n0+n)*H + c]);
    ha[n][128+c] = agg[(size_t)(n0+n)*H + c];
  }
  __syncthreads();
  float s[8];
  float bv = bu[c];
  #pragma unroll
  for (int n=0;n<8;n++) s[n] = bv;
  #pragma unroll 2
  for (int k=0;k<256;k++){
    float w = Wu[(size_t)k*H + c];
    #pragma unroll
    for (int n=0;n<8;n++) s[n] = fmaf(ha[n][k], w, s[n]);
  }
  float gc = g[c], bc = bln[c];
  #pragma unroll 1
  for (int n=0;n<8;n++){
    int nn = n0+n;
    upre[(size_t)nn*H + c] = f2bf(s[n]);
    float2 ms = blockSum2_128(s[n], s[n]*s[n], sb);
    float mu = ms.x*(1.f/128.f);
    float var = ms.y*(1.f/128.f) - mu*mu;
    float rstd = rsqrtf(var + 1e-5f);
    if (c == 0){ lnst[(size_t)nn*2+0] = mu; lnst[(size_t)nn*2+1] = rstd; }
    float uh = (s[n] - mu)*rstd;
    float un = uh*gc + bc;
    hout[(size_t)nn*H + c] = f2bf(ha[n][c] + siluf(un));
    size_t idx = (size_t)nn*H + c;
    T[idx] = f2bf(Tf[idx]);
    Tf[idx] = 0.f;
  }
}

// ---------- final MLP fused fwd+bwd (8 nodes/block) ----------
__global__ __launch_bounds__(128) void final_fused(
    const u16* __restrict__ h, const float* __restrict__ Wo, const float* __restrict__ bo,
    const float* __restrict__ Wh1, const float* __restrict__ bh1v,
    const float* __restrict__ Wh2, float* __restrict__ dh)
{
  __shared__ float sh[8][128], sf[8][64], sdz[8][32], sdf[8][64];
  const int n0 = blockIdx.x*8, c = threadIdx.x;
  #pragma unroll
  for (int n=0;n<8;n++) sh[n][c] = bf2f(h[(size_t)(n0+n)*H + c]);
  __syncthreads();
  if (c < 64){
    float s[8]; float bv = bo[c];
    #pragma unroll
    for (int n=0;n<8;n++) s[n] = bv;
    #pragma unroll 2
    for (int k=0;k<128;k++){
      float w = Wo[(size_t)k*64 + c];
      #pragma unroll
      for (int n=0;n<8;n++) s[n] = fmaf(sh[n][k], w, s[n]);
    }
    #pragma unroll
    for (int n=0;n<8;n++) sf[n][c] = s[n];
  }
  __syncthreads();
  if (c < 32){
    float s[8]; float bv = bh1v[c];
    #pragma unroll
    for (int n=0;n<8;n++) s[n] = bv;
    #pragma unroll 2
    for (int j=0;j<64;j++){
      float w = Wh1[(size_t)j*32 + c];
      #pragma unroll
      for (int n=0;n<8;n++) s[n] = fmaf(sf[n][j], w, s[n]);
    }
    float w2 = Wh2[c];
    #pragma unroll
    for (int n=0;n<8;n++) sdz[n][c] = w2*dsilu(s[n]);
  }
  __syncthreads();
  if (c < 64){
    float s[8];
    #pragma unroll
    for (int n=0;n<8;n++) s[n] = 0.f;
    #pragma unroll 2
    for (int k=0;k<32;k++){
      float w = Wh1[(size_t)c*32 + k];
      #pragma unroll
      for (int n=0;n<8;n++) s[n] = fmaf(sdz[n][k], w, s[n]);
    }
    #pragma unroll
    for (int n=0;n<8;n++) sdf[n][c] = s[n];
  }
  __syncthreads();
  {
    float s[8];
    #pragma unroll
    for (int n=0;n<8;n++) s[n] = 0.f;
    #pragma unroll 2
    for (int j=0;j<64;j++){
      float w = Wo[(size_t)c*64 + j];
      #pragma unroll
      for (int n=0;n<8;n++) s[n] = fmaf(sdf[n][j], w, s[n]);
    }
    #pragma unroll
    for (int n=0;n<8;n++) dh[(size_t)(n0+n)*H + c] = s[n];
  }
}

// ---------- node update backward (8 nodes/block, fused dstmsg) ----------
__global__ __launch_bounds__(128) void upd_bwd(
    float* __restrict__ dh, float* __restrict__ dagg,
    const u16* __restrict__ upre, const float* __restrict__ lnst,
    const float* __restrict__ WuT, const u16* __restrict__ T,
    const float* __restrict__ WmT,
    const float* __restrict__ g, const float* __restrict__ bln)
{
  __shared__ float sh[8][128];
  __shared__ float qs[8][128];
  __shared__ float sb[4];
  const int n0 = blockIdx.x*8, c = threadIdx.x;
  const float gc = g[c], bc = bln[c];
  float dhv[8];
  #pragma unroll 1
  for (int n=0;n<8;n++){
    int nn = n0+n;
    float up   = bf2f(upre[(size_t)nn*H + c]);
    float mu   = lnst[(size_t)nn*2+0];
    float rstd = lnst[(size_t)nn*2+1];
    float uh = (up - mu)*rstd;
    float un = uh*gc + bc;
    dhv[n] = dh[(size_t)nn*H + c];
    float dun = dhv[n] * dsilu(un);
    float duh = dun * gc;
    float2 m12 = blockSum2_128(duh, duh*uh, sb);
    sh[n][c] = (duh - m12.x*(1.f/128.f) - uh*(m12.y*(1.f/128.f)))*rstd;
  }
  __syncthreads();
  float s0[8], s1[8];
  #pragma unroll
  for (int n=0;n<8;n++){ s0[n]=0.f; s1[n]=0.f; }
  #pragma unroll 2
  for (int k=0;k<128;k++){
    float w0 = WuT[(size_t)k*256 + c];
    float w1 = WuT[(size_t)k*256 + 128 + c];
    #pragma unroll
    for (int n=0;n<8;n++){
      float d = sh[n][k];
      s0[n] = fmaf(d, w0, s0[n]);
      s1[n] = fmaf(d, w1, s1[n]);
    }
  }
  #pragma unroll
  for (int n=0;n<8;n++){
    int nn = n0+n;
    dagg[(size_t)nn*H + c] = s1[n];
    qs[n][c] = s1[n] * bf2f(T[(size_t)nn*H + c]);
  }
  __syncthreads();
  float a2[8];
  #pragma unroll
  for (int n=0;n<8;n++) a2[n] = 0.f;
  #pragma unroll 2
  for (int k=0;k<128;k++){
    float w = WmT[(size_t)k*388 + 128 + c];
    #pragma unroll
    for (int n=0;n<8;n++) a2[n] = fmaf(qs[n][k], w, a2[n]);
  }
  #pragma unroll
  for (int n=0;n<8;n++) dh[(size_t)(n0+n)*H + c] = dhv[n] + s0[n] + a2[n];
}

// ---------- dist -> dpos ----------
__global__ void rel_bwd(const float* __restrict__ y, const float* __restrict__ dist,
                        const float* __restrict__ ddist, const int* __restrict__ ei,
                        float* __restrict__ dpos){
  int e = blockIdx.x*256 + threadIdx.x;
  if (e >= NE) return;
  int s = ei[e], d = ei[NE+e];
  float gsc = ddist[e]/dist[e];
  #pragma unroll
  for (int i=0;i<3;i++){
    float dr = gsc*(y[(size_t)d*6+i] - y[(size_t)s*6+i]);
    atomicAdd(&dpos[(size_t)d*3+i],  dr);
    atomicAdd(&dpos[(size_t)s*3+i], -dr);
  }
}

// ---------- output (f32) ----------
__global__ void out_k(const float* __restrict__ y, const float* __restrict__ dpos,
                      float* __restrict__ out){
  int n = blockIdx.x*256 + threadIdx.x;
  if (n >= NN) return;
  #pragma unroll
  for (int i=0;i<3;i++) out[(size_t)n*6+i]   =  y[(size_t)n*6+3+i];
  #pragma unroll
  for (int i=0;i<3;i++) out[(size_t)n*6+3+i] = -dpos[(size_t)n*3+i];
}

// ---------- host ----------
extern "C" void kernel_launch(void* const* d_in, const int* in_sizes, int n_in,
                              void* d_out, int out_size, void* d_ws, size_t ws_size,
                              hipStream_t stream)
{
  const float* y   = (const float*)d_in[0];
  const float* x   = (const float*)d_in[1];
  const float* ea  = (const float*)d_in[2];
  const int*   ei  = (const int*)d_in[3];
  const float* Wn  = (const float*)d_in[4];
  const float* bn  = (const float*)d_in[5];
  const float* We5 = (const float*)d_in[6];
  const float* be5 = (const float*)d_in[7];
  const float* Wm  = (const float*)d_in[8];
  const float* bm  = (const float*)d_in[9];
  const float* Wu  = (const float*)d_in[10];
  const float* bu  = (const float*)d_in[11];
  const float* lg  = (const float*)d_in[12];
  const float* lb  = (const float*)d_in[13];
  const float* We  = (const float*)d_in[14];
  const float* beu = (const float*)d_in[15];
  const float* Wo  = (const float*)d_in[16];
  const float* bo  = (const float*)d_in[17];
  const float* Wh1 = (const float*)d_in[18];
  const float* bh1v= (const float*)d_in[19];
  const float* Wh2 = (const float*)d_in[20];
  float* out = (float*)d_out;

  if (ws_size < WS_NEED){
    diag_k<<<1, 1, 0, stream>>>(out, 4000.f + (float)(ws_size >> 20));
    return;
  }

  char* ws = (char*)d_ws;
  u16*   h5    = (u16*)  (ws + OFF_H5);
  u16*   upre  = (u16*)  (ws + OFF_UPRE);
  float* lnst  = (float*)(ws + OFF_LNST);
  u16*   T     = (u16*)  (ws + OFF_T);
  u16*   eb    = (u16*)  (ws + OFF_E);
  u16*   de    = (u16*)  (ws + OFF_DE);
  float* aggd  = (float*)(ws + OFF_AGG);
  float* dh    = (float*)(ws + OFF_DH);     // Tf during forward
  float* dist  = (float*)(ws + OFF_DIST);
  float* ddist = (float*)(ws + OFF_DDIST);
  float* dpos  = (float*)(ws + OFF_DPOS);
  float* WmT   = (float*)(ws + OFF_WMT);
  float* WeT   = (float*)(ws + OFF_WET);
  float* WuT   = (float*)(ws + OFF_WUT);
  int*   perm_d= (int*)  (ws + OFF_PD);
  int*   perm_s= (int*)  (ws + OFF_PS);
  int*   curd  = (int*)  (ws + OFF_CURD);
  int*   curs  = (int*)  (ws + OFF_CURS);
  u16*   WmP   = (u16*)  (ws + OFF_WMP);
  u16*   WeP   = (u16*)  (ws + OFF_WEP);
  u16*   WmTP  = (u16*)  (ws + OFF_WMTP);
  u16*   WeTP  = (u16*)  (ws + OFF_WETP);

  hipMemsetAsync(ddist, 0, (size_t)NE*4, stream);
  hipMemsetAsync(dpos,  0, (size_t)NN*3*4, stream);
  hipMemsetAsync(de,    0, NEH*2, stream);
  hipMemsetAsync(dh,    0, NNH*4, stream);
  hipMemsetAsync(curd,  0, (size_t)NN*4, stream);
  hipMemsetAsync(curs,  0, (size_t)NN*4, stream);

  transpose_w<<<512, 256, 0, stream>>>(Wm, We, Wu, WmT, WeT, WuT);
  pack_k<<<NL*12*8, 64, 0, stream>>>(Wm,  WmP,  12, 8,  128, (size_t)385*128, 49152);
  pack_k<<<NL*12*8, 64, 0, stream>>>(We,  WeP,  12, 8,  128, (size_t)384*128, 49152);
  pack_k<<<NL*4*24, 64, 0, stream>>>(WmT, WmTP, 4,  24, 388, (size_t)128*388, 49152);
  pack_k<<<NL*4*24, 64, 0, stream>>>(WeT, WeTP, 4,  24, 384, (size_t)128*384, 49152);

  node_emb<<<NN, 128, 0, stream>>>(x, Wn, bn, h5);
  edge_emb<<<NE/2, 256, 0, stream>>>(ea, We5, be5, eb);
  rel_dist<<<NE/256, 256, 0, stream>>>(y, ei, dist);

  hist_k<<<NE/256, 256, 0, stream>>>(ei, curs, curd);
  scan_k<<<1, 256, 0, stream>>>(curd, curs);
  fill_k<<<NE/256, 256, 0, stream>>>(ei, curs, curd, perm_s, perm_d);

  // ---- forward ----
  for (int l=0; l<NL; l++){
    hipMemsetAsync(aggd, 0, NNH*4, stream);
    efwd<0><<<NE/128, 256, 0, stream>>>(h5 + l*NNH, eb, dist, ei, perm_d,
        Wm + (size_t)l*385*H, bm + (size_t)l*H, WmP + (size_t)l*49152, aggd, dh);
    upd_fwd<<<NN/8, 128, 0, stream>>>(h5 + l*NNH, aggd,
        Wu + (size_t)l*256*H, bu + (size_t)l*H,
        lg + (size_t)l*H, lb + (size_t)l*H,
        upre + l*NNH, lnst + (size_t)l*NN*2, h5 + (l+1)*NNH,
        T + l*NNH, dh);
    if (l < NL-1){
      efwd<1><<<NE/128, 256, 0, stream>>>(h5 + (l+1)*NNH, eb, nullptr, ei, nullptr,
          We + (size_t)l*384*H, beu + (size_t)l*H, WeP + (size_t)l*49152, nullptr, nullptr);
    }
  }

  final_fused<<<NN/8, 128, 0, stream>>>(h5 + (size_t)NL*NNH, Wo, bo, Wh1, bh1v, Wh2, dh);

  // ---- backward ----
  for (int l=NL-1; l>=0; l--){
    if (l < NL-1){
      edge_emb<<<NE/2, 256, 0, stream>>>(ea, We5, be5, eb);
      for (int k=0; k<l; k++){
        efwd<1><<<NE/128, 256, 0, stream>>>(h5 + (k+1)*NNH, eb, nullptr, ei, nullptr,
            We + (size_t)k*384*H, beu + (size_t)k*H, WeP + (size_t)k*49152, nullptr, nullptr);
      }
      ebwd<1><<<NE/128, 256, 0, stream>>>(h5 + (l+1)*NNH, eb, nullptr, ei, perm_s,
          We + (size_t)l*384*H, beu + (size_t)l*H, nullptr, nullptr,
          WeP + (size_t)l*49152, WeTP + (size_t)l*49152, dh, de, nullptr);
    }
    upd_bwd<<<NN/8, 128, 0, stream>>>(dh, aggd, upre + l*NNH, lnst + (size_t)l*NN*2,
        WuT + (size_t)l*128*256, T + l*NNH, WmT + (size_t)l*128*388,
        lg + (size_t)l*H, lb + (size_t)l*H);
    ebwd<0><<<NE/128, 256, 0, stream>>>(h5 + l*NNH, eb, dist, ei, perm_s,
        Wm + (size_t)l*385*H, bm + (size_t)l*H, aggd, WmT + (size_t)l*128*388,
        WmP + (size_t)l*49152, WmTP + (size_t)l*49152, dh, de, ddist);
  }

  rel_bwd<<<NE/256, 256, 0, stream>>>(y, dist, ddist, ei, dpos);
  out_k<<<(NN+255)/256, 256, 0, stream>>>(y, dpos, out);
}